// Round 1
// baseline (337.264 us; speedup 1.0000x reference)
//
#include <hip/hip_runtime.h>
#include <hip/hip_bf16.h>

#define NSEQ   4096
#define BATCH  4
#define CDIM   128
#define NHEAD  4
#define HD     32
#define HIDDEN 512

typedef __attribute__((ext_vector_type(8))) short short8;
typedef __attribute__((ext_vector_type(4))) float f32x4;

__device__ inline unsigned short f2bf(float f){
  union { float f; unsigned u; } v; v.f = f;
  return (unsigned short)((v.u + 0x7fffu + ((v.u >> 16) & 1u)) >> 16);
}
__device__ inline float bf2f(unsigned short u){
  union { unsigned u; float f; } v; v.u = ((unsigned)u) << 16;
  return v.f;
}

// ---------------- Kernel 1: LN1 + QKV GEMM -> q/k/v bf16 [3][B*H][N][32] ----
__global__ __launch_bounds__(512) void k_ln1_qkv(
    const float* __restrict__ x, const float* __restrict__ g,
    const float* __restrict__ b, const float* __restrict__ w,
    const float* __restrict__ bias, unsigned short* __restrict__ qkv)
{
  __shared__ float xn[16][128];
  const int tid = threadIdx.x;
  const int tok0 = blockIdx.x * 16;
  {
    const int wave = tid >> 6, lane = tid & 63;
    const int tl = wave * 2 + (lane >> 5);
    const int e = (lane & 31) * 4;
    const float4 xv = *(const float4*)(x + (size_t)(tok0 + tl) * 128 + e);
    float s  = xv.x + xv.y + xv.z + xv.w;
    float s2 = xv.x*xv.x + xv.y*xv.y + xv.z*xv.z + xv.w*xv.w;
    #pragma unroll
    for (int m = 1; m <= 16; m <<= 1){ s += __shfl_xor(s, m); s2 += __shfl_xor(s2, m); }
    const float mu = s * (1.f/128.f);
    const float rs = rsqrtf(s2 * (1.f/128.f) - mu*mu + 1e-5f);
    const float4 gv = *(const float4*)(g + e);
    const float4 bv = *(const float4*)(b + e);
    xn[tl][e+0] = (xv.x - mu) * rs * gv.x + bv.x;
    xn[tl][e+1] = (xv.y - mu) * rs * gv.y + bv.y;
    xn[tl][e+2] = (xv.z - mu) * rs * gv.z + bv.z;
    xn[tl][e+3] = (xv.w - mu) * rs * gv.w + bv.w;
  }
  __syncthreads();
  if (tid < 384){
    float acc[16];
    #pragma unroll
    for (int t = 0; t < 16; t++) acc[t] = 0.f;
    for (int k = 0; k < 128; k += 4){
      const float w0 = w[(k+0)*384 + tid];
      const float w1 = w[(k+1)*384 + tid];
      const float w2 = w[(k+2)*384 + tid];
      const float w3 = w[(k+3)*384 + tid];
      #pragma unroll
      for (int t = 0; t < 16; t++){
        const float4 xv = *(const float4*)&xn[t][k];
        acc[t] += xv.x*w0 + xv.y*w1 + xv.z*w2 + xv.w*w3;
      }
    }
    const float bi = bias[tid];
    const int sel = tid >> 7, cc = tid & 127, h = cc >> 5, d = cc & 31;
    const int bidx = tok0 >> 12, n0 = tok0 & (NSEQ - 1);
    unsigned short* dst = qkv + ((size_t)sel*16 + bidx*NHEAD + h) * NSEQ * HD + d;
    #pragma unroll
    for (int t = 0; t < 16; t++)
      dst[(size_t)(n0 + t) * HD] = f2bf(acc[t] + bi);
  }
}

// ---------------- Kernel 2: flash attention (bf16 MFMA, swapped operands) ---
__global__ __launch_bounds__(256) void k_attn(
    const unsigned short* __restrict__ qkv, float* __restrict__ attn_out)
{
  const int lane = threadIdx.x & 63, wave = threadIdx.x >> 6;
  const int bh = blockIdx.y;
  const int qbase = blockIdx.x * 64 + wave * 16;
  const unsigned short* Q = qkv + (size_t)bh * NSEQ * HD;
  const unsigned short* K = qkv + (size_t)(16 + bh) * NSEQ * HD;
  const unsigned short* V = qkv + (size_t)(32 + bh) * NSEQ * HD;
  const int r = lane & 15, cg = lane >> 4;
  const short8 qf = *(const short8*)(Q + (size_t)(qbase + r) * HD + cg * 8);
  f32x4 o0 = {0.f,0.f,0.f,0.f}, o1 = {0.f,0.f,0.f,0.f};
  const f32x4 zero = {0.f,0.f,0.f,0.f};
  float mq = -1e30f, lq = 0.f;
  const float SCL = 0.17677669529663687f * 1.4426950408889634f; // 1/sqrt(32)*log2(e)
  for (int kb = 0; kb < NSEQ; kb += 32){
    const short8 ka0 = *(const short8*)(K + (size_t)(kb +      r) * HD + cg * 8);
    const short8 ka1 = *(const short8*)(K + (size_t)(kb + 16 + r) * HD + cg * 8);
    // S^T tiles: lane holds kpos = kb + 16*tile + 4*cg + reg, q = qbase + r
    const f32x4 s0 = __builtin_amdgcn_mfma_f32_16x16x32_bf16(ka0, qf, zero, 0, 0, 0);
    const f32x4 s1 = __builtin_amdgcn_mfma_f32_16x16x32_bf16(ka1, qf, zero, 0, 0, 0);
    float tm = fmaxf(fmaxf(fmaxf(s0[0],s0[1]), fmaxf(s0[2],s0[3])),
                     fmaxf(fmaxf(s1[0],s1[1]), fmaxf(s1[2],s1[3])));
    tm = fmaxf(tm, __shfl_xor(tm, 16));
    tm = fmaxf(tm, __shfl_xor(tm, 32));
    const float mn = fmaxf(mq, tm);
    const float alpha = exp2f((mq - mn) * SCL);
    float p[8]; float ps = 0.f;
    #pragma unroll
    for (int i = 0; i < 4; i++){
      p[i]     = exp2f((s0[i] - mn) * SCL);
      p[4 + i] = exp2f((s1[i] - mn) * SCL);
      ps += p[i] + p[4 + i];
    }
    ps += __shfl_xor(ps, 16);
    ps += __shfl_xor(ps, 32);
    lq = lq * alpha + ps;
    mq = mn;
    #pragma unroll
    for (int i = 0; i < 4; i++){ o0[i] *= alpha; o1[i] *= alpha; }
    short8 pf, va0, va1;
    #pragma unroll
    for (int i = 0; i < 8; i++) pf[i] = (short)f2bf(p[i]);
    #pragma unroll
    for (int i = 0; i < 8; i++){
      const int row = kb + ((i >> 2) << 4) + 4 * cg + (i & 3);
      const unsigned uv = *(const unsigned*)(V + (size_t)row * HD + 2 * r);
      va0[i] = (short)(uv & 0xffffu);
      va1[i] = (short)(uv >> 16);
    }
    // O^T += V^T * P^T ; instance h covers d = 2*col + h
    o0 = __builtin_amdgcn_mfma_f32_16x16x32_bf16(va0, pf, o0, 0, 0, 0);
    o1 = __builtin_amdgcn_mfma_f32_16x16x32_bf16(va1, pf, o1, 0, 0, 0);
  }
  const float inv = 1.f / lq;
  const int b = bh >> 2, h = bh & 3;
  float* orow = attn_out + ((size_t)b * NSEQ + qbase + r) * CDIM + h * HD + cg * 8;
  #pragma unroll
  for (int j = 0; j < 4; j++){
    orow[2*j]   = o0[j] * inv;   // d = 8cg + 2j
    orow[2*j+1] = o1[j] * inv;   // d = 8cg + 2j + 1
  }
}

// ---------------- Kernel 3: proj + bias + residual -> out1 ; LN2 -> h bf16 --
__global__ __launch_bounds__(512) void k_proj_ln2(
    const float* __restrict__ attn, const float* __restrict__ x,
    const float* __restrict__ w, const float* __restrict__ bias,
    const float* __restrict__ g2, const float* __restrict__ b2,
    float* __restrict__ out1, unsigned short* __restrict__ h)
{
  __shared__ float sb[16][128];
  const int tid = threadIdx.x;
  const int tok0 = blockIdx.x * 16;
  for (int i = tid; i < 2048; i += 512)
    sb[i >> 7][i & 127] = attn[(size_t)tok0 * 128 + i];
  __syncthreads();
  const int j = tid & 127, grp = tid >> 7;
  float acc[4] = {0.f, 0.f, 0.f, 0.f};
  for (int k = 0; k < 128; k += 4){
    const float w0 = w[(k+0)*128 + j], w1 = w[(k+1)*128 + j];
    const float w2 = w[(k+2)*128 + j], w3 = w[(k+3)*128 + j];
    #pragma unroll
    for (int t = 0; t < 4; t++){
      const float4 xv = *(const float4*)&sb[grp*4 + t][k];
      acc[t] += xv.x*w0 + xv.y*w1 + xv.z*w2 + xv.w*w3;
    }
  }
  const float bi = bias[j];
  __syncthreads();
  #pragma unroll
  for (int t = 0; t < 4; t++){
    const int tl = grp*4 + t;
    const float v = acc[t] + bi + x[(size_t)(tok0 + tl)*128 + j];
    out1[(size_t)(tok0 + tl)*128 + j] = v;
    sb[tl][j] = v;
  }
  __syncthreads();
  const int wave = tid >> 6, lane = tid & 63;
  const int tl = wave*2 + (lane >> 5);
  const int e = (lane & 31) * 4;
  const float4 xv = *(const float4*)&sb[tl][e];
  float s  = xv.x + xv.y + xv.z + xv.w;
  float s2 = xv.x*xv.x + xv.y*xv.y + xv.z*xv.z + xv.w*xv.w;
  #pragma unroll
  for (int m = 1; m <= 16; m <<= 1){ s += __shfl_xor(s, m); s2 += __shfl_xor(s2, m); }
  const float mu = s * (1.f/128.f);
  const float rs = rsqrtf(s2 * (1.f/128.f) - mu*mu + 1e-5f);
  const float4 gv = *(const float4*)(g2 + e), bv = *(const float4*)(b2 + e);
  unsigned short* hr = h + (size_t)(tok0 + tl) * 128 + e;
  hr[0] = f2bf((xv.x - mu)*rs*gv.x + bv.x);
  hr[1] = f2bf((xv.y - mu)*rs*gv.y + bv.y);
  hr[2] = f2bf((xv.z - mu)*rs*gv.z + bv.z);
  hr[3] = f2bf((xv.w - mu)*rs*gv.w + bv.w);
}

// ---------------- Kernel 4: MLP1 + exact GELU -> a bf16 ---------------------
__global__ __launch_bounds__(512) void k_mlp1(
    const unsigned short* __restrict__ h, const float* __restrict__ w,
    const float* __restrict__ bias, unsigned short* __restrict__ a)
{
  __shared__ float hs[16][128];
  const int tid = threadIdx.x;
  const int tok0 = blockIdx.x * 16;
  for (int i = tid; i < 2048; i += 512)
    hs[i >> 7][i & 127] = bf2f(h[(size_t)tok0 * 128 + i]);
  __syncthreads();
  float acc[16];
  #pragma unroll
  for (int t = 0; t < 16; t++) acc[t] = 0.f;
  for (int k = 0; k < 128; k += 4){
    const float w0 = w[(k+0)*512 + tid], w1 = w[(k+1)*512 + tid];
    const float w2 = w[(k+2)*512 + tid], w3 = w[(k+3)*512 + tid];
    #pragma unroll
    for (int t = 0; t < 16; t++){
      const float4 xv = *(const float4*)&hs[t][k];
      acc[t] += xv.x*w0 + xv.y*w1 + xv.z*w2 + xv.w*w3;
    }
  }
  const float bi = bias[tid];
  #pragma unroll
  for (int t = 0; t < 16; t++){
    const float v = acc[t] + bi;
    const float ge = 0.5f * v * (1.f + erff(v * 0.70710678118f));
    a[(size_t)(tok0 + t) * 512 + tid] = f2bf(ge);
  }
}

// ---------------- Kernel 5: MLP2 + bias + residual -> out -------------------
__global__ __launch_bounds__(512) void k_mlp2(
    const unsigned short* __restrict__ a, const float* __restrict__ w,
    const float* __restrict__ bias, const float* __restrict__ out1,
    float* __restrict__ out)
{
  __shared__ float as[16][512];
  const int tid = threadIdx.x;
  const int tok0 = blockIdx.x * 16;
  for (int i = tid; i < 8192; i += 512)
    as[i >> 9][i & 511] = bf2f(a[(size_t)tok0 * 512 + i]);
  __syncthreads();
  const int j = tid & 127, grp = tid >> 7;
  float acc[4] = {0.f, 0.f, 0.f, 0.f};
  for (int k = 0; k < 512; k += 4){
    const float w0 = w[(k+0)*128 + j], w1 = w[(k+1)*128 + j];
    const float w2 = w[(k+2)*128 + j], w3 = w[(k+3)*128 + j];
    #pragma unroll
    for (int t = 0; t < 4; t++){
      const float4 av = *(const float4*)&as[grp*4 + t][k];
      acc[t] += av.x*w0 + av.y*w1 + av.z*w2 + av.w*w3;
    }
  }
  const float bi = bias[j];
  #pragma unroll
  for (int t = 0; t < 4; t++){
    const int tok = tok0 + grp*4 + t;
    out[(size_t)tok*128 + j] = acc[t] + bi + out1[(size_t)tok*128 + j];
  }
}

extern "C" void kernel_launch(void* const* d_in, const int* in_sizes, int n_in,
                              void* d_out, int out_size, void* d_ws, size_t ws_size,
                              hipStream_t stream)
{
  const float* x      = (const float*)d_in[0];
  const float* ln1_g  = (const float*)d_in[1];
  const float* ln1_b  = (const float*)d_in[2];
  const float* qkv_w  = (const float*)d_in[3];
  const float* qkv_b  = (const float*)d_in[4];
  const float* proj_w = (const float*)d_in[5];
  const float* proj_b = (const float*)d_in[6];
  const float* ln2_g  = (const float*)d_in[7];
  const float* ln2_b  = (const float*)d_in[8];
  const float* mlp_w1 = (const float*)d_in[9];
  const float* mlp_b1 = (const float*)d_in[10];
  const float* mlp_w2 = (const float*)d_in[11];
  const float* mlp_b2 = (const float*)d_in[12];

  char* ws = (char*)d_ws;
  unsigned short* qkv = (unsigned short*)(ws);                 // 12.58 MB
  float*          attn = (float*)(ws + 12582912);              //  8.39 MB
  float*          out1 = (float*)(ws + 20971520);              //  8.39 MB
  unsigned short* hbuf = (unsigned short*)(ws + 29360128);     //  4.19 MB
  unsigned short* abuf = (unsigned short*)(ws + 33554432);     // 16.78 MB
  float* out = (float*)d_out;

  hipLaunchKernelGGL(k_ln1_qkv, dim3(1024), dim3(512), 0, stream,
                     x, ln1_g, ln1_b, qkv_w, qkv_b, qkv);
  hipLaunchKernelGGL(k_attn, dim3(64, 16), dim3(256), 0, stream, qkv, attn);
  hipLaunchKernelGGL(k_proj_ln2, dim3(1024), dim3(512), 0, stream,
                     attn, x, proj_w, proj_b, ln2_g, ln2_b, out1, hbuf);
  hipLaunchKernelGGL(k_mlp1, dim3(1024), dim3(512), 0, stream,
                     hbuf, mlp_w1, mlp_b1, abuf);
  hipLaunchKernelGGL(k_mlp2, dim3(1024), dim3(512), 0, stream,
                     abuf, mlp_w2, mlp_b2, out1, out);
}

// Round 2
// 295.503 us; speedup vs baseline: 1.1413x; 1.1413x over previous
//
#include <hip/hip_runtime.h>
#include <hip/hip_bf16.h>

#define NSEQ   4096
#define BATCH  4
#define CDIM   128
#define NHEAD  4
#define HD     32
#define HIDDEN 512

typedef __attribute__((ext_vector_type(8))) short short8;
typedef __attribute__((ext_vector_type(4))) short short4v;
typedef __attribute__((ext_vector_type(4))) float f32x4;
typedef __attribute__((ext_vector_type(4))) unsigned u32x4;

__device__ inline unsigned short f2bf(float f){
  union { float f; unsigned u; } v; v.f = f;
  return (unsigned short)((v.u + 0x7fffu + ((v.u >> 16) & 1u)) >> 16);
}
__device__ inline float bf2f(unsigned short u){
  union { unsigned u; float f; } v; v.u = ((unsigned)u) << 16;
  return v.f;
}

// ---------------- Kernel 1: LN1 + QKV GEMM ----------------------------------
// Q planes [bh][n][32], pre-scaled by (1/sqrt(32))*log2(e).
// K planes [bh][n][32] (row-major).
// V planes in MFMA-ready layout: idx = ((nblk*2+parity)*16 + col)*32 + cg*8 + i
//   where n = nblk*32 + 16*(i>>2) + 4*cg + (i&3), d = 2*col + parity.
__global__ __launch_bounds__(512) void k_ln1_qkv(
    const float* __restrict__ x, const float* __restrict__ g,
    const float* __restrict__ b, const float* __restrict__ w,
    const float* __restrict__ bias, unsigned short* __restrict__ qkv)
{
  __shared__ float xn[16][128];
  const int tid = threadIdx.x;
  const int tok0 = blockIdx.x * 16;
  {
    const int wave = tid >> 6, lane = tid & 63;
    const int tl = wave * 2 + (lane >> 5);
    const int e = (lane & 31) * 4;
    const float4 xv = *(const float4*)(x + (size_t)(tok0 + tl) * 128 + e);
    float s  = xv.x + xv.y + xv.z + xv.w;
    float s2 = xv.x*xv.x + xv.y*xv.y + xv.z*xv.z + xv.w*xv.w;
    #pragma unroll
    for (int m = 1; m <= 16; m <<= 1){ s += __shfl_xor(s, m); s2 += __shfl_xor(s2, m); }
    const float mu = s * (1.f/128.f);
    const float rs = rsqrtf(s2 * (1.f/128.f) - mu*mu + 1e-5f);
    const float4 gv = *(const float4*)(g + e);
    const float4 bv = *(const float4*)(b + e);
    xn[tl][e+0] = (xv.x - mu) * rs * gv.x + bv.x;
    xn[tl][e+1] = (xv.y - mu) * rs * gv.y + bv.y;
    xn[tl][e+2] = (xv.z - mu) * rs * gv.z + bv.z;
    xn[tl][e+3] = (xv.w - mu) * rs * gv.w + bv.w;
  }
  __syncthreads();
  if (tid < 384){
    float acc[16];
    #pragma unroll
    for (int t = 0; t < 16; t++) acc[t] = 0.f;
    for (int k = 0; k < 128; k += 4){
      const float w0 = w[(k+0)*384 + tid];
      const float w1 = w[(k+1)*384 + tid];
      const float w2 = w[(k+2)*384 + tid];
      const float w3 = w[(k+3)*384 + tid];
      #pragma unroll
      for (int t = 0; t < 16; t++){
        const float4 xv = *(const float4*)&xn[t][k];
        acc[t] += xv.x*w0 + xv.y*w1 + xv.z*w2 + xv.w*w3;
      }
    }
    const float bi = bias[tid];
    const int sel = tid >> 7, cc = tid & 127, h = cc >> 5, d = cc & 31;
    const int bidx = tok0 >> 12, n0 = tok0 & (NSEQ - 1);
    unsigned short* plane = qkv + ((size_t)sel*16 + bidx*NHEAD + h) * NSEQ * HD;
    if (sel == 0){
      const float SCL = 0.17677669529663687f * 1.4426950408889634f;
      unsigned short* dst = plane + (size_t)n0 * HD + d;
      #pragma unroll
      for (int t = 0; t < 16; t++)
        dst[(size_t)t * HD] = f2bf((acc[t] + bi) * SCL);
    } else if (sel == 1){
      unsigned short* dst = plane + (size_t)n0 * HD + d;
      #pragma unroll
      for (int t = 0; t < 16; t++)
        dst[(size_t)t * HD] = f2bf(acc[t] + bi);
    } else {
      // V interleaved layout; n0 is a multiple of 16 so nblk/tile-bit constant.
      const size_t base = (((size_t)(n0 >> 5) * 2 + (d & 1)) * 16 + (d >> 1)) * 32
                          + ((n0 >> 4) & 1) * 4;
      #pragma unroll
      for (int gq = 0; gq < 4; gq++){
        short4v pk;
        #pragma unroll
        for (int j = 0; j < 4; j++) pk[j] = (short)f2bf(acc[gq*4 + j] + bi);
        *(short4v*)(plane + base + gq * 8) = pk;
      }
    }
  }
}

// ---------------- Kernel 2: flash attention (max-free, bf16 MFMA) -----------
__global__ __launch_bounds__(256) void k_attn(
    const unsigned short* __restrict__ qkv, float* __restrict__ attn_out)
{
  const int lane = threadIdx.x & 63, wave = threadIdx.x >> 6;
  const int bh = blockIdx.y;
  const int qbase = blockIdx.x * 64 + wave * 16;
  const unsigned short* Q  = qkv + (size_t)bh * NSEQ * HD;
  const unsigned short* K  = qkv + (size_t)(16 + bh) * NSEQ * HD;
  const unsigned short* Vt = qkv + (size_t)(32 + bh) * NSEQ * HD;
  const int r = lane & 15, cg = lane >> 4;
  const short8 qf = *(const short8*)(Q + (size_t)(qbase + r) * HD + cg * 8);
  const unsigned short* kp = K + (size_t)r * HD + cg * 8;
  const unsigned short* vp = Vt + (size_t)(r * 32 + cg * 8);
  f32x4 o0 = {0.f,0.f,0.f,0.f}, o1 = {0.f,0.f,0.f,0.f};
  const f32x4 zero = {0.f,0.f,0.f,0.f};
  float lsum = 0.f;
  #pragma unroll 2
  for (int kb = 0; kb < NSEQ; kb += 32){
    const short8 ka0 = *(const short8*)(kp);
    const short8 ka1 = *(const short8*)(kp + 512);
    const short8 va0 = *(const short8*)(vp);
    const short8 va1 = *(const short8*)(vp + 512);
    kp += 1024; vp += 1024;
    // S^T tiles: lane holds kpos, q = qbase + r. Q pre-scaled -> p = 2^s.
    const f32x4 s0 = __builtin_amdgcn_mfma_f32_16x16x32_bf16(ka0, qf, zero, 0, 0, 0);
    const f32x4 s1 = __builtin_amdgcn_mfma_f32_16x16x32_bf16(ka1, qf, zero, 0, 0, 0);
    float p0[4], p1[4];
    #pragma unroll
    for (int i = 0; i < 4; i++){
      p0[i] = __builtin_amdgcn_exp2f(s0[i]);
      p1[i] = __builtin_amdgcn_exp2f(s1[i]);
      lsum += p0[i]; lsum += p1[i];
    }
    u32x4 pu;
    {
      unsigned a0, a1, a2, a3;
      asm("v_cvt_pk_bf16_f32 %0, %1, %2" : "=v"(a0) : "v"(p0[0]), "v"(p0[1]));
      asm("v_cvt_pk_bf16_f32 %0, %1, %2" : "=v"(a1) : "v"(p0[2]), "v"(p0[3]));
      asm("v_cvt_pk_bf16_f32 %0, %1, %2" : "=v"(a2) : "v"(p1[0]), "v"(p1[1]));
      asm("v_cvt_pk_bf16_f32 %0, %1, %2" : "=v"(a3) : "v"(p1[2]), "v"(p1[3]));
      pu[0] = a0; pu[1] = a1; pu[2] = a2; pu[3] = a3;
    }
    const short8 pf = __builtin_bit_cast(short8, pu);
    // O^T += V^T * P^T ; instance covers d = 2*col + parity
    o0 = __builtin_amdgcn_mfma_f32_16x16x32_bf16(va0, pf, o0, 0, 0, 0);
    o1 = __builtin_amdgcn_mfma_f32_16x16x32_bf16(va1, pf, o1, 0, 0, 0);
  }
  lsum += __shfl_xor(lsum, 16);
  lsum += __shfl_xor(lsum, 32);
  const float inv = 1.f / lsum;
  const int b = bh >> 2, h = bh & 3;
  float* orow = attn_out + ((size_t)b * NSEQ + qbase + r) * CDIM + h * HD + cg * 8;
  #pragma unroll
  for (int j = 0; j < 4; j++){
    orow[2*j]   = o0[j] * inv;   // d = 8cg + 2j
    orow[2*j+1] = o1[j] * inv;   // d = 8cg + 2j + 1
  }
}

// ---------------- Kernel 3: proj + bias + residual -> out1 ; LN2 -> h bf16 --
__global__ __launch_bounds__(512) void k_proj_ln2(
    const float* __restrict__ attn, const float* __restrict__ x,
    const float* __restrict__ w, const float* __restrict__ bias,
    const float* __restrict__ g2, const float* __restrict__ b2,
    float* __restrict__ out1, unsigned short* __restrict__ h)
{
  __shared__ float sb[16][128];
  const int tid = threadIdx.x;
  const int tok0 = blockIdx.x * 16;
  for (int i = tid; i < 2048; i += 512)
    sb[i >> 7][i & 127] = attn[(size_t)tok0 * 128 + i];
  __syncthreads();
  const int j = tid & 127, grp = tid >> 7;
  float acc[4] = {0.f, 0.f, 0.f, 0.f};
  for (int k = 0; k < 128; k += 4){
    const float w0 = w[(k+0)*128 + j], w1 = w[(k+1)*128 + j];
    const float w2 = w[(k+2)*128 + j], w3 = w[(k+3)*128 + j];
    #pragma unroll
    for (int t = 0; t < 4; t++){
      const float4 xv = *(const float4*)&sb[grp*4 + t][k];
      acc[t] += xv.x*w0 + xv.y*w1 + xv.z*w2 + xv.w*w3;
    }
  }
  const float bi = bias[j];
  __syncthreads();
  #pragma unroll
  for (int t = 0; t < 4; t++){
    const int tl = grp*4 + t;
    const float v = acc[t] + bi + x[(size_t)(tok0 + tl)*128 + j];
    out1[(size_t)(tok0 + tl)*128 + j] = v;
    sb[tl][j] = v;
  }
  __syncthreads();
  const int wave = tid >> 6, lane = tid & 63;
  const int tl = wave*2 + (lane >> 5);
  const int e = (lane & 31) * 4;
  const float4 xv = *(const float4*)&sb[tl][e];
  float s  = xv.x + xv.y + xv.z + xv.w;
  float s2 = xv.x*xv.x + xv.y*xv.y + xv.z*xv.z + xv.w*xv.w;
  #pragma unroll
  for (int m = 1; m <= 16; m <<= 1){ s += __shfl_xor(s, m); s2 += __shfl_xor(s2, m); }
  const float mu = s * (1.f/128.f);
  const float rs = rsqrtf(s2 * (1.f/128.f) - mu*mu + 1e-5f);
  const float4 gv = *(const float4*)(g2 + e), bv = *(const float4*)(b2 + e);
  unsigned short* hr = h + (size_t)(tok0 + tl) * 128 + e;
  hr[0] = f2bf((xv.x - mu)*rs*gv.x + bv.x);
  hr[1] = f2bf((xv.y - mu)*rs*gv.y + bv.y);
  hr[2] = f2bf((xv.z - mu)*rs*gv.z + bv.z);
  hr[3] = f2bf((xv.w - mu)*rs*gv.w + bv.w);
}

// ---------------- Kernel 4: MLP1 + exact GELU -> a bf16 ---------------------
__global__ __launch_bounds__(512) void k_mlp1(
    const unsigned short* __restrict__ h, const float* __restrict__ w,
    const float* __restrict__ bias, unsigned short* __restrict__ a)
{
  __shared__ float hs[16][128];
  const int tid = threadIdx.x;
  const int tok0 = blockIdx.x * 16;
  for (int i = tid; i < 2048; i += 512)
    hs[i >> 7][i & 127] = bf2f(h[(size_t)tok0 * 128 + i]);
  __syncthreads();
  float acc[16];
  #pragma unroll
  for (int t = 0; t < 16; t++) acc[t] = 0.f;
  for (int k = 0; k < 128; k += 4){
    const float w0 = w[(k+0)*512 + tid], w1 = w[(k+1)*512 + tid];
    const float w2 = w[(k+2)*512 + tid], w3 = w[(k+3)*512 + tid];
    #pragma unroll
    for (int t = 0; t < 16; t++){
      const float4 xv = *(const float4*)&hs[t][k];
      acc[t] += xv.x*w0 + xv.y*w1 + xv.z*w2 + xv.w*w3;
    }
  }
  const float bi = bias[tid];
  #pragma unroll
  for (int t = 0; t < 16; t++){
    const float v = acc[t] + bi;
    const float ge = 0.5f * v * (1.f + erff(v * 0.70710678118f));
    a[(size_t)(tok0 + t) * 512 + tid] = f2bf(ge);
  }
}

// ---------------- Kernel 5: MLP2 + bias + residual -> out -------------------
__global__ __launch_bounds__(512) void k_mlp2(
    const unsigned short* __restrict__ a, const float* __restrict__ w,
    const float* __restrict__ bias, const float* __restrict__ out1,
    float* __restrict__ out)
{
  __shared__ float as[16][512];
  const int tid = threadIdx.x;
  const int tok0 = blockIdx.x * 16;
  for (int i = tid; i < 8192; i += 512)
    as[i >> 9][i & 511] = bf2f(a[(size_t)tok0 * 512 + i]);
  __syncthreads();
  const int j = tid & 127, grp = tid >> 7;
  float acc[4] = {0.f, 0.f, 0.f, 0.f};
  for (int k = 0; k < 512; k += 4){
    const float w0 = w[(k+0)*128 + j], w1 = w[(k+1)*128 + j];
    const float w2 = w[(k+2)*128 + j], w3 = w[(k+3)*128 + j];
    #pragma unroll
    for (int t = 0; t < 4; t++){
      const float4 av = *(const float4*)&as[grp*4 + t][k];
      acc[t] += av.x*w0 + av.y*w1 + av.z*w2 + av.w*w3;
    }
  }
  const float bi = bias[j];
  #pragma unroll
  for (int t = 0; t < 4; t++){
    const int tok = tok0 + grp*4 + t;
    out[(size_t)tok*128 + j] = acc[t] + bi + out1[(size_t)tok*128 + j];
  }
}

extern "C" void kernel_launch(void* const* d_in, const int* in_sizes, int n_in,
                              void* d_out, int out_size, void* d_ws, size_t ws_size,
                              hipStream_t stream)
{
  const float* x      = (const float*)d_in[0];
  const float* ln1_g  = (const float*)d_in[1];
  const float* ln1_b  = (const float*)d_in[2];
  const float* qkv_w  = (const float*)d_in[3];
  const float* qkv_b  = (const float*)d_in[4];
  const float* proj_w = (const float*)d_in[5];
  const float* proj_b = (const float*)d_in[6];
  const float* ln2_g  = (const float*)d_in[7];
  const float* ln2_b  = (const float*)d_in[8];
  const float* mlp_w1 = (const float*)d_in[9];
  const float* mlp_b1 = (const float*)d_in[10];
  const float* mlp_w2 = (const float*)d_in[11];
  const float* mlp_b2 = (const float*)d_in[12];

  char* ws = (char*)d_ws;
  unsigned short* qkv = (unsigned short*)(ws);                 // 12.58 MB
  float*          attn = (float*)(ws + 12582912);              //  8.39 MB
  float*          out1 = (float*)(ws + 20971520);              //  8.39 MB
  unsigned short* hbuf = (unsigned short*)(ws + 29360128);     //  4.19 MB
  unsigned short* abuf = (unsigned short*)(ws + 33554432);     // 16.78 MB
  float* out = (float*)d_out;

  hipLaunchKernelGGL(k_ln1_qkv, dim3(1024), dim3(512), 0, stream,
                     x, ln1_g, ln1_b, qkv_w, qkv_b, qkv);
  hipLaunchKernelGGL(k_attn, dim3(64, 16), dim3(256), 0, stream, qkv, attn);
  hipLaunchKernelGGL(k_proj_ln2, dim3(1024), dim3(512), 0, stream,
                     attn, x, proj_w, proj_b, ln2_g, ln2_b, out1, hbuf);
  hipLaunchKernelGGL(k_mlp1, dim3(1024), dim3(512), 0, stream,
                     hbuf, mlp_w1, mlp_b1, abuf);
  hipLaunchKernelGGL(k_mlp2, dim3(1024), dim3(512), 0, stream,
                     abuf, mlp_w2, mlp_b2, out1, out);
}

// Round 3
// 160.667 us; speedup vs baseline: 2.0992x; 1.8392x over previous
//
#include <hip/hip_runtime.h>
#include <hip/hip_bf16.h>
#include <math.h>

#define NSEQ   4096
#define CDIM   128
#define HD     32

typedef __attribute__((ext_vector_type(8))) short short8;
typedef __attribute__((ext_vector_type(4))) short short4v;
typedef __attribute__((ext_vector_type(4))) float f32x4;

#define QSCL (0.17677669529663687f * 1.4426950408889634f)  // 1/sqrt(32)*log2(e)

__device__ inline unsigned short f2bf(float f){
  union { float f; unsigned u; } v; v.f = f;
  return (unsigned short)((v.u + 0x7fffu + ((v.u >> 16) & 1u)) >> 16);
}

// ---- ws layout (bytes) -----------------------------------------------------
// 0        : wpack u16 [196608]  (wq@0, wp@49152, w1@65536, w2@131072)
// 393216   : bqs   f32 [384]     (qkv bias, Q part pre-scaled)
// 524288   : qkv   u16 48 planes x 131072   (Q[0..15], K[16..31], Vfrag[32..47])
//            (later reused: attn_bf16 u16 [16384][128] @ 524288)
// 13107200 : part_o f32 [4][16][4096][32]   (later reused: out1/h/abuf)
// 46661632 : part_l f32 [4][16][4096]
// reuse:     out1 f32 @13107200, h u16 @21495808, abuf u16 @25690112

// ---------------- K0: pack weights to MFMA B-fragment layout ----------------
// B-frag for tile (ct,kt): elem i of lane = w[kt*32+(lane>>4)*8+i][ct*16+(lane&15)]
__global__ __launch_bounds__(256) void k_pack(
    const float* __restrict__ qkv_w, const float* __restrict__ qkv_b,
    const float* __restrict__ proj_w, const float* __restrict__ mlp_w1,
    const float* __restrict__ mlp_w2, unsigned short* __restrict__ wpack,
    float* __restrict__ bqs)
{
  const int gt = blockIdx.x * 256 + threadIdx.x;
  const int tile = gt >> 6, lane = gt & 63;
  const float* src; int N, KT, toff, dstoff; float scale = 1.f;
  if (tile < 96)       { src = qkv_w;  N = 384; KT = 4;  toff = tile;       dstoff = 0; }
  else if (tile < 128) { src = proj_w; N = 128; KT = 4;  toff = tile - 96;  dstoff = 49152; }
  else if (tile < 256) { src = mlp_w1; N = 512; KT = 4;  toff = tile - 128; dstoff = 65536; }
  else                 { src = mlp_w2; N = 128; KT = 16; toff = tile - 256; dstoff = 131072; }
  const int ct = toff / KT, kt = toff % KT;
  if (tile < 96 && ct < 8) scale = QSCL;   // Q columns
  const int row0 = kt * 32 + (lane >> 4) * 8, col = ct * 16 + (lane & 15);
  short8 v;
  #pragma unroll
  for (int i = 0; i < 8; i++)
    v[i] = (short)f2bf(src[(size_t)(row0 + i) * N + col] * scale);
  *(short8*)(wpack + dstoff + ((size_t)(ct * KT + kt) * 64 + lane) * 8) = v;
  if (gt < 384) bqs[gt] = qkv_b[gt] * (gt < 128 ? QSCL : 1.f);
}

// ---------------- K1: LN1 + QKV MFMA GEMM -----------------------------------
__global__ __launch_bounds__(512) void k_qkv(
    const float* __restrict__ x, const float* __restrict__ g,
    const float* __restrict__ b, const unsigned short* __restrict__ wpack,
    const float* __restrict__ bqs, unsigned short* __restrict__ qkv)
{
  __shared__ unsigned short xn[64 * 128];   // fragment layout, XOR-swizzled rows
  const int tid = threadIdx.x;
  const int tok0 = blockIdx.x * 64;
  { // LN phase: 16 groups of 32 lanes, 4 tokens each
    const int grp = tid >> 5, l = tid & 31;
    #pragma unroll
    for (int it = 0; it < 4; it++){
      const int t = it * 16 + grp;
      const float4 xv = *(const float4*)(x + (size_t)(tok0 + t) * 128 + l * 4);
      float s  = xv.x + xv.y + xv.z + xv.w;
      float s2 = xv.x*xv.x + xv.y*xv.y + xv.z*xv.z + xv.w*xv.w;
      #pragma unroll
      for (int m = 1; m <= 16; m <<= 1){ s += __shfl_xor(s, m); s2 += __shfl_xor(s2, m); }
      const float mu = s * (1.f/128.f);
      const float rs = rsqrtf(s2 * (1.f/128.f) - mu*mu + 1e-5f);
      const int e = l * 4;
      const float4 gv = *(const float4*)(g + e), bv = *(const float4*)(b + e);
      short4v pk;
      pk[0] = (short)f2bf((xv.x - mu)*rs*gv.x + bv.x);
      pk[1] = (short)f2bf((xv.y - mu)*rs*gv.y + bv.y);
      pk[2] = (short)f2bf((xv.z - mu)*rs*gv.z + bv.z);
      pk[3] = (short)f2bf((xv.w - mu)*rs*gv.w + bv.w);
      const int bl = l >> 1;                       // (kt*4+cg) block id
      const int slot = bl * 64 + (t & 48) + ((t & 15) ^ bl);
      *(short4v*)(xn + slot * 8 + (l & 1) * 4) = pk;
    }
  }
  __syncthreads();
  const int wv = tid >> 6, lane = tid & 63, r = lane & 15, cg = lane >> 4;
  const int rt = wv & 3, ct0 = (wv >> 2) * 12;
  short8 af[4];
  #pragma unroll
  for (int kt = 0; kt < 4; kt++){
    const int bl = kt * 4 + cg;
    const int slot = bl * 64 + rt * 16 + (r ^ bl);
    af[kt] = *(const short8*)(xn + slot * 8);
  }
  const int bidx = tok0 >> 12, nloc = (tok0 & (NSEQ - 1)) + rt * 16 + cg * 4;
  for (int ct = ct0; ct < ct0 + 12; ct++){
    f32x4 acc = {0.f, 0.f, 0.f, 0.f};
    const unsigned short* bp = wpack + ((size_t)(ct * 4) * 64 + lane) * 8;
    #pragma unroll
    for (int kt = 0; kt < 4; kt++)
      acc = __builtin_amdgcn_mfma_f32_16x16x32_bf16(af[kt], *(const short8*)(bp + kt * 512), acc, 0, 0, 0);
    const int col = ct * 16 + r;
    const float bi = bqs[col];
    if (ct < 16){                                  // Q or K: row-major [n][32]
      const int sel = ct >> 3;                     // 0=Q, 1=K
      const int cc = col & 127, h = cc >> 5, d = cc & 31;
      unsigned short* plane = qkv + ((size_t)(sel * 16) + bidx * 4 + h) * (NSEQ * HD);
      #pragma unroll
      for (int reg = 0; reg < 4; reg++)
        plane[(size_t)(nloc + reg) * HD + d] = f2bf(acc[reg] + bi);
    } else {                                       // V: PV-fragment layout
      const int vct = ct - 16, h = vct >> 1, half = vct & 1;
      unsigned short* plane = qkv + ((size_t)32 + bidx * 4 + h) * (NSEQ * HD);
      const size_t ntile = (size_t)((tok0 & (NSEQ - 1)) >> 5) + (rt >> 1);
      const size_t vo = (ntile * 2 + half) * 512 + lane * 8 + (rt & 1) * 4;
      short4v pk;
      #pragma unroll
      for (int reg = 0; reg < 4; reg++) pk[reg] = (short)f2bf(acc[reg] + bi);
      *(short4v*)(plane + vo) = pk;
    }
  }
}

// ---------------- K2: flash attention, KV-split, max-free -------------------
__global__ __launch_bounds__(256) void k_attn(
    const unsigned short* __restrict__ qkv, float* __restrict__ part_o,
    float* __restrict__ part_l)
{
  const int lane = threadIdx.x & 63, wave = threadIdx.x >> 6;
  const int chunk = blockIdx.y, bh = blockIdx.z;
  const int qbase = blockIdx.x * 64 + wave * 16;
  const int kv0 = chunk * 1024;
  const unsigned short* Q  = qkv + (size_t)bh * (NSEQ * HD);
  const unsigned short* K  = qkv + (size_t)(16 + bh) * (NSEQ * HD);
  const unsigned short* Vt = qkv + (size_t)(32 + bh) * (NSEQ * HD);
  const int r = lane & 15, cg = lane >> 4;
  const short8 qf = *(const short8*)(Q + (size_t)(qbase + r) * HD + cg * 8);
  const unsigned short* kp = K + (size_t)(kv0 + r) * HD + cg * 8;
  const unsigned short* vp = Vt + (size_t)(kv0 >> 5) * 1024 + lane * 8;
  f32x4 o0 = {0.f,0.f,0.f,0.f}, o1 = {0.f,0.f,0.f,0.f};
  const f32x4 zero = {0.f,0.f,0.f,0.f};
  float lsum = 0.f;
  #pragma unroll 2
  for (int it = 0; it < 32; it++){
    const short8 ka0 = *(const short8*)(kp);
    const short8 ka1 = *(const short8*)(kp + 512);
    const short8 va0 = *(const short8*)(vp);
    const short8 va1 = *(const short8*)(vp + 512);
    kp += 1024; vp += 1024;
    const f32x4 s0 = __builtin_amdgcn_mfma_f32_16x16x32_bf16(ka0, qf, zero, 0, 0, 0);
    const f32x4 s1 = __builtin_amdgcn_mfma_f32_16x16x32_bf16(ka1, qf, zero, 0, 0, 0);
    float p0[4], p1[4];
    #pragma unroll
    for (int i = 0; i < 4; i++){
      p0[i] = __builtin_amdgcn_exp2f(s0[i]);
      p1[i] = __builtin_amdgcn_exp2f(s1[i]);
      lsum += p0[i]; lsum += p1[i];
    }
    unsigned a0, a1, a2, a3;
    asm("v_cvt_pk_bf16_f32 %0, %1, %2" : "=v"(a0) : "v"(p0[0]), "v"(p0[1]));
    asm("v_cvt_pk_bf16_f32 %0, %1, %2" : "=v"(a1) : "v"(p0[2]), "v"(p0[3]));
    asm("v_cvt_pk_bf16_f32 %0, %1, %2" : "=v"(a2) : "v"(p1[0]), "v"(p1[1]));
    asm("v_cvt_pk_bf16_f32 %0, %1, %2" : "=v"(a3) : "v"(p1[2]), "v"(p1[3]));
    union { unsigned u[4]; short8 s; } pc;
    pc.u[0] = a0; pc.u[1] = a1; pc.u[2] = a2; pc.u[3] = a3;
    o0 = __builtin_amdgcn_mfma_f32_16x16x32_bf16(va0, pc.s, o0, 0, 0, 0);
    o1 = __builtin_amdgcn_mfma_f32_16x16x32_bf16(va1, pc.s, o1, 0, 0, 0);
  }
  lsum += __shfl_xor(lsum, 16);
  lsum += __shfl_xor(lsum, 32);
  // lane holds o for q = lane&15; o0 -> d = 4*cg + reg, o1 -> d = 16 + 4*cg + reg
  float* po = part_o + (((size_t)(chunk * 16 + bh) * NSEQ) + qbase + r) * HD;
  *(f32x4*)(po + cg * 4)      = o0;
  *(f32x4*)(po + 16 + cg * 4) = o1;
  if (lane < 16)
    part_l[(size_t)(chunk * 16 + bh) * NSEQ + qbase + r] = lsum;
}

// ---------------- K3: combine partials -> attn bf16 [16384][128] ------------
__global__ __launch_bounds__(256) void k_reduce(
    const float* __restrict__ part_o, const float* __restrict__ part_l,
    unsigned short* __restrict__ attnb)
{
  const int gt = blockIdx.x * 256 + threadIdx.x;
  const int j = gt >> 3, d0 = (gt & 7) * 4;
  const int q = j & (NSEQ - 1), bh = j >> 12;
  float4 s = {0.f, 0.f, 0.f, 0.f};
  float lsum = 0.f;
  #pragma unroll
  for (int c = 0; c < 4; c++){
    const float4 v = *(const float4*)(part_o + (((size_t)(c * 16 + bh) * NSEQ) + q) * HD + d0);
    s.x += v.x; s.y += v.y; s.z += v.z; s.w += v.w;
    lsum += part_l[(size_t)(c * 16 + bh) * NSEQ + q];
  }
  const float inv = 1.f / lsum;
  short4v pk;
  pk[0] = (short)f2bf(s.x * inv); pk[1] = (short)f2bf(s.y * inv);
  pk[2] = (short)f2bf(s.z * inv); pk[3] = (short)f2bf(s.w * inv);
  *(short4v*)(attnb + ((size_t)(bh >> 2) * NSEQ + q) * CDIM + (bh & 3) * HD + d0) = pk;
}

// ---------------- K4: proj MFMA + bias + residual -> out1 ; LN2 -> h --------
__global__ __launch_bounds__(512) void k_proj(
    const unsigned short* __restrict__ attnb, const float* __restrict__ x,
    const unsigned short* __restrict__ wpack, const float* __restrict__ pb,
    const float* __restrict__ g2, const float* __restrict__ b2,
    float* __restrict__ out1, unsigned short* __restrict__ h)
{
  __shared__ float sb[64 * 128];
  const int tid = threadIdx.x;
  const int tok0 = blockIdx.x * 64;
  const int wv = tid >> 6, lane = tid & 63, r = lane & 15, cg = lane >> 4;
  const int rt = wv & 3, ct0 = (wv >> 2) * 4;
  short8 af[4];
  #pragma unroll
  for (int kt = 0; kt < 4; kt++)
    af[kt] = *(const short8*)(attnb + (size_t)(tok0 + rt * 16 + r) * CDIM + kt * 32 + cg * 8);
  const unsigned short* wp = wpack + 49152;
  for (int ct = ct0; ct < ct0 + 4; ct++){
    f32x4 acc = {0.f, 0.f, 0.f, 0.f};
    const unsigned short* bp = wp + ((size_t)(ct * 4) * 64 + lane) * 8;
    #pragma unroll
    for (int kt = 0; kt < 4; kt++)
      acc = __builtin_amdgcn_mfma_f32_16x16x32_bf16(af[kt], *(const short8*)(bp + kt * 512), acc, 0, 0, 0);
    const int col = ct * 16 + r;
    const float bi = pb[col];
    #pragma unroll
    for (int reg = 0; reg < 4; reg++){
      const int tl = rt * 16 + cg * 4 + reg;
      sb[tl * 128 + col] = acc[reg] + bi + x[(size_t)(tok0 + tl) * 128 + col];
    }
  }
  __syncthreads();
  { // LN2 phase
    const int grp = tid >> 5, l = tid & 31;
    #pragma unroll
    for (int it = 0; it < 4; it++){
      const int t = it * 16 + grp;
      const float4 xv = *(const float4*)(sb + t * 128 + l * 4);
      float s  = xv.x + xv.y + xv.z + xv.w;
      float s2 = xv.x*xv.x + xv.y*xv.y + xv.z*xv.z + xv.w*xv.w;
      #pragma unroll
      for (int m = 1; m <= 16; m <<= 1){ s += __shfl_xor(s, m); s2 += __shfl_xor(s2, m); }
      const float mu = s * (1.f/128.f);
      const float rs = rsqrtf(s2 * (1.f/128.f) - mu*mu + 1e-5f);
      const int e = l * 4;
      *(float4*)(out1 + (size_t)(tok0 + t) * 128 + e) = xv;
      const float4 gv = *(const float4*)(g2 + e), bv = *(const float4*)(b2 + e);
      short4v pk;
      pk[0] = (short)f2bf((xv.x - mu)*rs*gv.x + bv.x);
      pk[1] = (short)f2bf((xv.y - mu)*rs*gv.y + bv.y);
      pk[2] = (short)f2bf((xv.z - mu)*rs*gv.z + bv.z);
      pk[3] = (short)f2bf((xv.w - mu)*rs*gv.w + bv.w);
      *(short4v*)(h + (size_t)(tok0 + t) * 128 + e) = pk;
    }
  }
}

// ---------------- K5: MLP1 MFMA + exact GELU -> abuf bf16 -------------------
__global__ __launch_bounds__(512) void k_mlp1(
    const unsigned short* __restrict__ h, const unsigned short* __restrict__ wpack,
    const float* __restrict__ b1, unsigned short* __restrict__ abuf)
{
  const int tid = threadIdx.x;
  const int tok0 = blockIdx.x * 64;
  const int wv = tid >> 6, lane = tid & 63, r = lane & 15, cg = lane >> 4;
  const int rt = wv & 3, ct0 = (wv >> 2) * 16;
  short8 af[4];
  #pragma unroll
  for (int kt = 0; kt < 4; kt++)
    af[kt] = *(const short8*)(h + (size_t)(tok0 + rt * 16 + r) * CDIM + kt * 32 + cg * 8);
  const unsigned short* w1 = wpack + 65536;
  for (int ct = ct0; ct < ct0 + 16; ct++){
    f32x4 acc = {0.f, 0.f, 0.f, 0.f};
    const unsigned short* bp = w1 + ((size_t)(ct * 4) * 64 + lane) * 8;
    #pragma unroll
    for (int kt = 0; kt < 4; kt++)
      acc = __builtin_amdgcn_mfma_f32_16x16x32_bf16(af[kt], *(const short8*)(bp + kt * 512), acc, 0, 0, 0);
    const int col = ct * 16 + r;
    const float bi = b1[col];
    #pragma unroll
    for (int reg = 0; reg < 4; reg++){
      const float v = acc[reg] + bi;
      const float ge = 0.5f * v * (1.f + erff(v * 0.70710678118f));
      abuf[(size_t)(tok0 + rt * 16 + cg * 4 + reg) * 512 + col] = f2bf(ge);
    }
  }
}

// ---------------- K6: MLP2 MFMA + bias + residual -> out --------------------
__global__ __launch_bounds__(512) void k_mlp2(
    const unsigned short* __restrict__ abuf, const unsigned short* __restrict__ wpack,
    const float* __restrict__ b2, const float* __restrict__ out1,
    float* __restrict__ out)
{
  const int tid = threadIdx.x;
  const int tok0 = blockIdx.x * 64;
  const int wv = tid >> 6, lane = tid & 63, r = lane & 15, cg = lane >> 4;
  const int rt = wv & 3, ct0 = (wv >> 2) * 4;
  const unsigned short* w2 = wpack + 131072;
  f32x4 acc[4] = {{0.f,0.f,0.f,0.f},{0.f,0.f,0.f,0.f},{0.f,0.f,0.f,0.f},{0.f,0.f,0.f,0.f}};
  for (int kt = 0; kt < 16; kt++){
    const short8 af = *(const short8*)(abuf + (size_t)(tok0 + rt * 16 + r) * 512 + kt * 32 + cg * 8);
    #pragma unroll
    for (int c = 0; c < 4; c++){
      const unsigned short* bp = w2 + ((size_t)((ct0 + c) * 16 + kt) * 64 + lane) * 8;
      acc[c] = __builtin_amdgcn_mfma_f32_16x16x32_bf16(af, *(const short8*)(bp), acc[c], 0, 0, 0);
    }
  }
  #pragma unroll
  for (int c = 0; c < 4; c++){
    const int col = (ct0 + c) * 16 + r;
    const float bi = b2[col];
    #pragma unroll
    for (int reg = 0; reg < 4; reg++){
      const size_t n = tok0 + rt * 16 + cg * 4 + reg;
      out[n * 128 + col] = acc[c][reg] + bi + out1[n * 128 + col];
    }
  }
}

extern "C" void kernel_launch(void* const* d_in, const int* in_sizes, int n_in,
                              void* d_out, int out_size, void* d_ws, size_t ws_size,
                              hipStream_t stream)
{
  const float* x      = (const float*)d_in[0];
  const float* ln1_g  = (const float*)d_in[1];
  const float* ln1_b  = (const float*)d_in[2];
  const float* qkv_w  = (const float*)d_in[3];
  const float* qkv_b  = (const float*)d_in[4];
  const float* proj_w = (const float*)d_in[5];
  const float* proj_b = (const float*)d_in[6];
  const float* ln2_g  = (const float*)d_in[7];
  const float* ln2_b  = (const float*)d_in[8];
  const float* mlp_w1 = (const float*)d_in[9];
  const float* mlp_b1 = (const float*)d_in[10];
  const float* mlp_w2 = (const float*)d_in[11];
  const float* mlp_b2 = (const float*)d_in[12];

  char* ws = (char*)d_ws;
  unsigned short* wpack = (unsigned short*)(ws);
  float*          bqs   = (float*)(ws + 393216);
  unsigned short* qkv   = (unsigned short*)(ws + 524288);
  unsigned short* attnb = (unsigned short*)(ws + 524288);      // reuses qkv region
  float*          part_o = (float*)(ws + 13107200);
  float*          part_l = (float*)(ws + 46661632);
  float*          out1  = (float*)(ws + 13107200);             // reuses part_o region
  unsigned short* hbuf  = (unsigned short*)(ws + 21495808);
  unsigned short* abuf  = (unsigned short*)(ws + 25690112);
  float* out = (float*)d_out;

  hipLaunchKernelGGL(k_pack, dim3(96), dim3(256), 0, stream,
                     qkv_w, qkv_b, proj_w, mlp_w1, mlp_w2, wpack, bqs);
  hipLaunchKernelGGL(k_qkv, dim3(256), dim3(512), 0, stream,
                     x, ln1_g, ln1_b, wpack, bqs, qkv);
  hipLaunchKernelGGL(k_attn, dim3(64, 4, 16), dim3(256), 0, stream,
                     qkv, part_o, part_l);
  hipLaunchKernelGGL(k_reduce, dim3(2048), dim3(256), 0, stream,
                     part_o, part_l, attnb);
  hipLaunchKernelGGL(k_proj, dim3(256), dim3(512), 0, stream,
                     attnb, x, wpack, proj_b, ln2_g, ln2_b, out1, hbuf);
  hipLaunchKernelGGL(k_mlp1, dim3(256), dim3(512), 0, stream,
                     hbuf, wpack, mlp_b1, abuf);
  hipLaunchKernelGGL(k_mlp2, dim3(256), dim3(512), 0, stream,
                     abuf, wpack, mlp_b2, out1, out);
}

// Round 4
// 113.535 us; speedup vs baseline: 2.9706x; 1.4151x over previous
//
#include <hip/hip_runtime.h>
#include <hip/hip_bf16.h>
#include <math.h>

#define NSEQ   4096
#define CDIM   128
#define HD     32

typedef __attribute__((ext_vector_type(8))) short short8;
typedef __attribute__((ext_vector_type(4))) short short4v;
typedef __attribute__((ext_vector_type(4))) float f32x4;

#define QSCL (0.17677669529663687f * 1.4426950408889634f)  // 1/sqrt(32)*log2(e)

__device__ inline unsigned short f2bf(float f){
  union { float f; unsigned u; } v; v.f = f;
  return (unsigned short)((v.u + 0x7fffu + ((v.u >> 16) & 1u)) >> 16);
}

__device__ inline void gload_lds16(const unsigned short* g, unsigned short* l){
  __builtin_amdgcn_global_load_lds(
      (const __attribute__((address_space(1))) void*)g,
      (__attribute__((address_space(3))) void*)l, 16, 0, 0);
}

// ---- ws layout (bytes) -----------------------------------------------------
// 0        : wpack u16 [196608]  (wq@0, wp@49152, w1@65536, w2@131072)
// 393216   : bqs   f32 [384]
// 524288   : qkv   u16 48 planes x 131072  (Q[0..15], K[16..31], Vfrag[32..47])
//            (later reused: attn_bf16 u16 @524288)
// 13107200 : part_o f32 [2][16][4096][32]  (16.78MB; later reused out1/h/abuf)
// 29884416 : part_l f32 [2][16][4096]      (512KB)
// reuse:     out1 f32 @13107200, h u16 @21495808, abuf u16 @25690112

// ---------------- K0: pack weights to MFMA B-fragment layout ----------------
__global__ __launch_bounds__(256) void k_pack(
    const float* __restrict__ qkv_w, const float* __restrict__ qkv_b,
    const float* __restrict__ proj_w, const float* __restrict__ mlp_w1,
    const float* __restrict__ mlp_w2, unsigned short* __restrict__ wpack,
    float* __restrict__ bqs)
{
  const int gt = blockIdx.x * 256 + threadIdx.x;
  const int tile = gt >> 6, lane = gt & 63;
  const float* src; int N, KT, toff, dstoff; float scale = 1.f;
  if (tile < 96)       { src = qkv_w;  N = 384; KT = 4;  toff = tile;       dstoff = 0; }
  else if (tile < 128) { src = proj_w; N = 128; KT = 4;  toff = tile - 96;  dstoff = 49152; }
  else if (tile < 256) { src = mlp_w1; N = 512; KT = 4;  toff = tile - 128; dstoff = 65536; }
  else                 { src = mlp_w2; N = 128; KT = 16; toff = tile - 256; dstoff = 131072; }
  const int ct = toff / KT, kt = toff % KT;
  if (tile < 96 && ct < 8) scale = QSCL;   // Q columns
  const int row0 = kt * 32 + (lane >> 4) * 8, col = ct * 16 + (lane & 15);
  short8 v;
  #pragma unroll
  for (int i = 0; i < 8; i++)
    v[i] = (short)f2bf(src[(size_t)(row0 + i) * N + col] * scale);
  *(short8*)(wpack + dstoff + ((size_t)(ct * KT + kt) * 64 + lane) * 8) = v;
  if (gt < 384) bqs[gt] = qkv_b[gt] * (gt < 128 ? QSCL : 1.f);
}

// ---------------- K1: LN1 + QKV MFMA GEMM -----------------------------------
__global__ __launch_bounds__(512) void k_qkv(
    const float* __restrict__ x, const float* __restrict__ g,
    const float* __restrict__ b, const unsigned short* __restrict__ wpack,
    const float* __restrict__ bqs, unsigned short* __restrict__ qkv)
{
  __shared__ unsigned short xn[64 * 128];
  const int tid = threadIdx.x;
  const int tok0 = blockIdx.x * 64;
  {
    const int grp = tid >> 5, l = tid & 31;
    #pragma unroll
    for (int it = 0; it < 4; it++){
      const int t = it * 16 + grp;
      const float4 xv = *(const float4*)(x + (size_t)(tok0 + t) * 128 + l * 4);
      float s  = xv.x + xv.y + xv.z + xv.w;
      float s2 = xv.x*xv.x + xv.y*xv.y + xv.z*xv.z + xv.w*xv.w;
      #pragma unroll
      for (int m = 1; m <= 16; m <<= 1){ s += __shfl_xor(s, m); s2 += __shfl_xor(s2, m); }
      const float mu = s * (1.f/128.f);
      const float rs = rsqrtf(s2 * (1.f/128.f) - mu*mu + 1e-5f);
      const int e = l * 4;
      const float4 gv = *(const float4*)(g + e), bv = *(const float4*)(b + e);
      short4v pk;
      pk[0] = (short)f2bf((xv.x - mu)*rs*gv.x + bv.x);
      pk[1] = (short)f2bf((xv.y - mu)*rs*gv.y + bv.y);
      pk[2] = (short)f2bf((xv.z - mu)*rs*gv.z + bv.z);
      pk[3] = (short)f2bf((xv.w - mu)*rs*gv.w + bv.w);
      const int bl = l >> 1;
      const int slot = bl * 64 + (t & 48) + ((t & 15) ^ bl);
      *(short4v*)(xn + slot * 8 + (l & 1) * 4) = pk;
    }
  }
  __syncthreads();
  const int wv = tid >> 6, lane = tid & 63, r = lane & 15, cg = lane >> 4;
  const int rt = wv & 3, ct0 = (wv >> 2) * 12;
  short8 af[4];
  #pragma unroll
  for (int kt = 0; kt < 4; kt++){
    const int bl = kt * 4 + cg;
    const int slot = bl * 64 + rt * 16 + (r ^ bl);
    af[kt] = *(const short8*)(xn + slot * 8);
  }
  const int bidx = tok0 >> 12, nloc = (tok0 & (NSEQ - 1)) + rt * 16 + cg * 4;
  for (int ct = ct0; ct < ct0 + 12; ct++){
    f32x4 acc = {0.f, 0.f, 0.f, 0.f};
    const unsigned short* bp = wpack + ((size_t)(ct * 4) * 64 + lane) * 8;
    #pragma unroll
    for (int kt = 0; kt < 4; kt++)
      acc = __builtin_amdgcn_mfma_f32_16x16x32_bf16(af[kt], *(const short8*)(bp + kt * 512), acc, 0, 0, 0);
    const int col = ct * 16 + r;
    const float bi = bqs[col];
    if (ct < 16){
      const int sel = ct >> 3;
      const int cc = col & 127, h = cc >> 5, d = cc & 31;
      unsigned short* plane = qkv + ((size_t)(sel * 16) + bidx * 4 + h) * (NSEQ * HD);
      #pragma unroll
      for (int reg = 0; reg < 4; reg++)
        plane[(size_t)(nloc + reg) * HD + d] = f2bf(acc[reg] + bi);
    } else {
      const int vct = ct - 16, h = vct >> 1, half = vct & 1;
      unsigned short* plane = qkv + ((size_t)32 + bidx * 4 + h) * (NSEQ * HD);
      const size_t ntile = (size_t)((tok0 & (NSEQ - 1)) >> 5) + (rt >> 1);
      const size_t vo = (ntile * 2 + half) * 512 + lane * 8 + (rt & 1) * 4;
      short4v pk;
      #pragma unroll
      for (int reg = 0; reg < 4; reg++) pk[reg] = (short)f2bf(acc[reg] + bi);
      *(short4v*)(plane + vo) = pk;
    }
  }
}

// ---------------- K2: flash attention, LDS-shared K/V, 2 q-tiles/wave -------
// grid (32, 2, 16); block 256. Block: 128 q rows, KV chunk 2048 keys.
__global__ __launch_bounds__(256, 4) void k_attn(
    const unsigned short* __restrict__ qkv, float* __restrict__ part_o,
    float* __restrict__ part_l)
{
  __shared__ unsigned short sk[2][1024];
  __shared__ unsigned short sv[2][1024];
  const int tid = threadIdx.x;
  const int lane = tid & 63, wv = tid >> 6;
  const int chunk = blockIdx.y, bh = blockIdx.z;
  const int qbase = blockIdx.x * 128 + wv * 32;
  const int kv0 = chunk * 2048;
  const unsigned short* Q  = qkv + (size_t)bh * (NSEQ * HD);
  const unsigned short* Kc = qkv + (size_t)(16 + bh) * (NSEQ * HD) + (size_t)kv0 * HD;
  const unsigned short* Vc = qkv + (size_t)(32 + bh) * (NSEQ * HD) + (size_t)(kv0 >> 5) * 1024;
  const int r = lane & 15, cg = lane >> 4;
  const short8 qf0 = *(const short8*)(Q + (size_t)(qbase + r) * HD + cg * 8);
  const short8 qf1 = *(const short8*)(Q + (size_t)(qbase + 16 + r) * HD + cg * 8);
  // staging: waves 0,1 -> K halves; waves 2,3 -> V halves (1KB each, linear)
  const unsigned short* gsrc = (wv < 2 ? Kc : Vc) + (size_t)(wv & 1) * 512 + lane * 8;
  unsigned short* ld0 = (wv < 2 ? sk[0] : sv[0]) + (wv & 1) * 512;
  unsigned short* ld1 = (wv < 2 ? sk[1] : sv[1]) + (wv & 1) * 512;
  f32x4 o00 = {0.f,0.f,0.f,0.f}, o01 = {0.f,0.f,0.f,0.f};
  f32x4 o10 = {0.f,0.f,0.f,0.f}, o11 = {0.f,0.f,0.f,0.f};
  const f32x4 zero = {0.f,0.f,0.f,0.f};
  float ls0 = 0.f, ls1 = 0.f;
  gload_lds16(gsrc, ld0);
  __syncthreads();
  for (int nt = 0; nt < 64; nt++){
    const int b = nt & 1;
    if (nt + 1 < 64)
      gload_lds16(gsrc + (size_t)(nt + 1) * 1024, b ? ld0 : ld1);
    const unsigned short* skb = sk[b];
    const unsigned short* svb = sv[b];
    const short8 ka0 = *(const short8*)(skb + r * 32 + cg * 8);
    const short8 ka1 = *(const short8*)(skb + 512 + r * 32 + cg * 8);
    const short8 va0 = *(const short8*)(svb + lane * 8);
    const short8 va1 = *(const short8*)(svb + 512 + lane * 8);
    const f32x4 s00 = __builtin_amdgcn_mfma_f32_16x16x32_bf16(ka0, qf0, zero, 0, 0, 0);
    const f32x4 s01 = __builtin_amdgcn_mfma_f32_16x16x32_bf16(ka1, qf0, zero, 0, 0, 0);
    const f32x4 s10 = __builtin_amdgcn_mfma_f32_16x16x32_bf16(ka0, qf1, zero, 0, 0, 0);
    const f32x4 s11 = __builtin_amdgcn_mfma_f32_16x16x32_bf16(ka1, qf1, zero, 0, 0, 0);
    float p00[4], p01[4], p10[4], p11[4];
    #pragma unroll
    for (int i = 0; i < 4; i++){
      p00[i] = __builtin_amdgcn_exp2f(s00[i]);
      p01[i] = __builtin_amdgcn_exp2f(s01[i]);
      p10[i] = __builtin_amdgcn_exp2f(s10[i]);
      p11[i] = __builtin_amdgcn_exp2f(s11[i]);
      ls0 += p00[i] + p01[i];
      ls1 += p10[i] + p11[i];
    }
    unsigned c0, c1, c2, c3, c4, c5, c6, c7;
    asm("v_cvt_pk_bf16_f32 %0, %1, %2" : "=v"(c0) : "v"(p00[0]), "v"(p00[1]));
    asm("v_cvt_pk_bf16_f32 %0, %1, %2" : "=v"(c1) : "v"(p00[2]), "v"(p00[3]));
    asm("v_cvt_pk_bf16_f32 %0, %1, %2" : "=v"(c2) : "v"(p01[0]), "v"(p01[1]));
    asm("v_cvt_pk_bf16_f32 %0, %1, %2" : "=v"(c3) : "v"(p01[2]), "v"(p01[3]));
    asm("v_cvt_pk_bf16_f32 %0, %1, %2" : "=v"(c4) : "v"(p10[0]), "v"(p10[1]));
    asm("v_cvt_pk_bf16_f32 %0, %1, %2" : "=v"(c5) : "v"(p10[2]), "v"(p10[3]));
    asm("v_cvt_pk_bf16_f32 %0, %1, %2" : "=v"(c6) : "v"(p11[0]), "v"(p11[1]));
    asm("v_cvt_pk_bf16_f32 %0, %1, %2" : "=v"(c7) : "v"(p11[2]), "v"(p11[3]));
    union { unsigned u[4]; short8 s; } pa, pb;
    pa.u[0] = c0; pa.u[1] = c1; pa.u[2] = c2; pa.u[3] = c3;
    pb.u[0] = c4; pb.u[1] = c5; pb.u[2] = c6; pb.u[3] = c7;
    o00 = __builtin_amdgcn_mfma_f32_16x16x32_bf16(va0, pa.s, o00, 0, 0, 0);
    o01 = __builtin_amdgcn_mfma_f32_16x16x32_bf16(va1, pa.s, o01, 0, 0, 0);
    o10 = __builtin_amdgcn_mfma_f32_16x16x32_bf16(va0, pb.s, o10, 0, 0, 0);
    o11 = __builtin_amdgcn_mfma_f32_16x16x32_bf16(va1, pb.s, o11, 0, 0, 0);
    __syncthreads();
  }
  ls0 += __shfl_xor(ls0, 16); ls0 += __shfl_xor(ls0, 32);
  ls1 += __shfl_xor(ls1, 16); ls1 += __shfl_xor(ls1, 32);
  float* po = part_o + (((size_t)(chunk * 16 + bh) * NSEQ) + qbase + r) * HD;
  *(f32x4*)(po + cg * 4)      = o00;
  *(f32x4*)(po + 16 + cg * 4) = o01;
  *(f32x4*)(po + 16 * HD + cg * 4)      = o10;
  *(f32x4*)(po + 16 * HD + 16 + cg * 4) = o11;
  if (lane < 16){
    part_l[(size_t)(chunk * 16 + bh) * NSEQ + qbase + r] = ls0;
    part_l[(size_t)(chunk * 16 + bh) * NSEQ + qbase + 16 + r] = ls1;
  }
}

// ---------------- K3: combine partials -> attn bf16 [16384][128] ------------
__global__ __launch_bounds__(256) void k_reduce(
    const float* __restrict__ part_o, const float* __restrict__ part_l,
    unsigned short* __restrict__ attnb)
{
  const int gt = blockIdx.x * 256 + threadIdx.x;
  const int j = gt >> 3, d0 = (gt & 7) * 4;
  const int q = j & (NSEQ - 1), bh = j >> 12;
  float4 s = {0.f, 0.f, 0.f, 0.f};
  float lsum = 0.f;
  #pragma unroll
  for (int c = 0; c < 2; c++){
    const float4 v = *(const float4*)(part_o + (((size_t)(c * 16 + bh) * NSEQ) + q) * HD + d0);
    s.x += v.x; s.y += v.y; s.z += v.z; s.w += v.w;
    lsum += part_l[(size_t)(c * 16 + bh) * NSEQ + q];
  }
  const float inv = 1.f / lsum;
  short4v pk;
  pk[0] = (short)f2bf(s.x * inv); pk[1] = (short)f2bf(s.y * inv);
  pk[2] = (short)f2bf(s.z * inv); pk[3] = (short)f2bf(s.w * inv);
  *(short4v*)(attnb + ((size_t)(bh >> 2) * NSEQ + q) * CDIM + (bh & 3) * HD + d0) = pk;
}

// ---------------- K4: proj MFMA + bias + residual -> out1 ; LN2 -> h --------
__global__ __launch_bounds__(512) void k_proj(
    const unsigned short* __restrict__ attnb, const float* __restrict__ x,
    const unsigned short* __restrict__ wpack, const float* __restrict__ pb,
    const float* __restrict__ g2, const float* __restrict__ b2,
    float* __restrict__ out1, unsigned short* __restrict__ h)
{
  __shared__ float sb[64 * 128];
  const int tid = threadIdx.x;
  const int tok0 = blockIdx.x * 64;
  const int wv = tid >> 6, lane = tid & 63, r = lane & 15, cg = lane >> 4;
  const int rt = wv & 3, ct0 = (wv >> 2) * 4;
  short8 af[4];
  #pragma unroll
  for (int kt = 0; kt < 4; kt++)
    af[kt] = *(const short8*)(attnb + (size_t)(tok0 + rt * 16 + r) * CDIM + kt * 32 + cg * 8);
  const unsigned short* wp = wpack + 49152;
  for (int ct = ct0; ct < ct0 + 4; ct++){
    f32x4 acc = {0.f, 0.f, 0.f, 0.f};
    const unsigned short* bp = wp + ((size_t)(ct * 4) * 64 + lane) * 8;
    #pragma unroll
    for (int kt = 0; kt < 4; kt++)
      acc = __builtin_amdgcn_mfma_f32_16x16x32_bf16(af[kt], *(const short8*)(bp + kt * 512), acc, 0, 0, 0);
    const int col = ct * 16 + r;
    const float bi = pb[col];
    #pragma unroll
    for (int reg = 0; reg < 4; reg++){
      const int tl = rt * 16 + cg * 4 + reg;
      sb[tl * 128 + col] = acc[reg] + bi + x[(size_t)(tok0 + tl) * 128 + col];
    }
  }
  __syncthreads();
  {
    const int grp = tid >> 5, l = tid & 31;
    #pragma unroll
    for (int it = 0; it < 4; it++){
      const int t = it * 16 + grp;
      const float4 xv = *(const float4*)(sb + t * 128 + l * 4);
      float s  = xv.x + xv.y + xv.z + xv.w;
      float s2 = xv.x*xv.x + xv.y*xv.y + xv.z*xv.z + xv.w*xv.w;
      #pragma unroll
      for (int m = 1; m <= 16; m <<= 1){ s += __shfl_xor(s, m); s2 += __shfl_xor(s2, m); }
      const float mu = s * (1.f/128.f);
      const float rs = rsqrtf(s2 * (1.f/128.f) - mu*mu + 1e-5f);
      const int e = l * 4;
      *(float4*)(out1 + (size_t)(tok0 + t) * 128 + e) = xv;
      const float4 gv = *(const float4*)(g2 + e), bv = *(const float4*)(b2 + e);
      short4v pk;
      pk[0] = (short)f2bf((xv.x - mu)*rs*gv.x + bv.x);
      pk[1] = (short)f2bf((xv.y - mu)*rs*gv.y + bv.y);
      pk[2] = (short)f2bf((xv.z - mu)*rs*gv.z + bv.z);
      pk[3] = (short)f2bf((xv.w - mu)*rs*gv.w + bv.w);
      *(short4v*)(h + (size_t)(tok0 + t) * 128 + e) = pk;
    }
  }
}

// ---------------- K5: MLP1 MFMA + exact GELU -> abuf bf16 -------------------
__global__ __launch_bounds__(512) void k_mlp1(
    const unsigned short* __restrict__ h, const unsigned short* __restrict__ wpack,
    const float* __restrict__ b1, unsigned short* __restrict__ abuf)
{
  const int tid = threadIdx.x;
  const int tok0 = blockIdx.x * 64;
  const int wv = tid >> 6, lane = tid & 63, r = lane & 15, cg = lane >> 4;
  const int rt = wv & 3, ct0 = (wv >> 2) * 16;
  short8 af[4];
  #pragma unroll
  for (int kt = 0; kt < 4; kt++)
    af[kt] = *(const short8*)(h + (size_t)(tok0 + rt * 16 + r) * CDIM + kt * 32 + cg * 8);
  const unsigned short* w1 = wpack + 65536;
  for (int ct = ct0; ct < ct0 + 16; ct++){
    f32x4 acc = {0.f, 0.f, 0.f, 0.f};
    const unsigned short* bp = w1 + ((size_t)(ct * 4) * 64 + lane) * 8;
    #pragma unroll
    for (int kt = 0; kt < 4; kt++)
      acc = __builtin_amdgcn_mfma_f32_16x16x32_bf16(af[kt], *(const short8*)(bp + kt * 512), acc, 0, 0, 0);
    const int col = ct * 16 + r;
    const float bi = b1[col];
    #pragma unroll
    for (int reg = 0; reg < 4; reg++){
      const float v = acc[reg] + bi;
      const float ge = 0.5f * v * (1.f + erff(v * 0.70710678118f));
      abuf[(size_t)(tok0 + rt * 16 + cg * 4 + reg) * 512 + col] = f2bf(ge);
    }
  }
}

// ---------------- K6: MLP2 MFMA + bias + residual -> out --------------------
__global__ __launch_bounds__(512) void k_mlp2(
    const unsigned short* __restrict__ abuf, const unsigned short* __restrict__ wpack,
    const float* __restrict__ b2, const float* __restrict__ out1,
    float* __restrict__ out)
{
  const int tid = threadIdx.x;
  const int tok0 = blockIdx.x * 64;
  const int wv = tid >> 6, lane = tid & 63, r = lane & 15, cg = lane >> 4;
  const int rt = wv & 3, ct0 = (wv >> 2) * 4;
  const unsigned short* w2 = wpack + 131072;
  f32x4 acc[4] = {{0.f,0.f,0.f,0.f},{0.f,0.f,0.f,0.f},{0.f,0.f,0.f,0.f},{0.f,0.f,0.f,0.f}};
  for (int kt = 0; kt < 16; kt++){
    const short8 af = *(const short8*)(abuf + (size_t)(tok0 + rt * 16 + r) * 512 + kt * 32 + cg * 8);
    #pragma unroll
    for (int c = 0; c < 4; c++){
      const unsigned short* bp = w2 + ((size_t)((ct0 + c) * 16 + kt) * 64 + lane) * 8;
      acc[c] = __builtin_amdgcn_mfma_f32_16x16x32_bf16(af, *(const short8*)(bp), acc[c], 0, 0, 0);
    }
  }
  #pragma unroll
  for (int c = 0; c < 4; c++){
    const int col = (ct0 + c) * 16 + r;
    const float bi = b2[col];
    #pragma unroll
    for (int reg = 0; reg < 4; reg++){
      const size_t n = tok0 + rt * 16 + cg * 4 + reg;
      out[n * 128 + col] = acc[c][reg] + bi + out1[n * 128 + col];
    }
  }
}

extern "C" void kernel_launch(void* const* d_in, const int* in_sizes, int n_in,
                              void* d_out, int out_size, void* d_ws, size_t ws_size,
                              hipStream_t stream)
{
  const float* x      = (const float*)d_in[0];
  const float* ln1_g  = (const float*)d_in[1];
  const float* ln1_b  = (const float*)d_in[2];
  const float* qkv_w  = (const float*)d_in[3];
  const float* qkv_b  = (const float*)d_in[4];
  const float* proj_w = (const float*)d_in[5];
  const float* proj_b = (const float*)d_in[6];
  const float* ln2_g  = (const float*)d_in[7];
  const float* ln2_b  = (const float*)d_in[8];
  const float* mlp_w1 = (const float*)d_in[9];
  const float* mlp_b1 = (const float*)d_in[10];
  const float* mlp_w2 = (const float*)d_in[11];
  const float* mlp_b2 = (const float*)d_in[12];

  char* ws = (char*)d_ws;
  unsigned short* wpack = (unsigned short*)(ws);
  float*          bqs   = (float*)(ws + 393216);
  unsigned short* qkv   = (unsigned short*)(ws + 524288);
  unsigned short* attnb = (unsigned short*)(ws + 524288);      // reuses qkv region
  float*          part_o = (float*)(ws + 13107200);
  float*          part_l = (float*)(ws + 29884416);
  float*          out1  = (float*)(ws + 13107200);             // reuses part_o region
  unsigned short* hbuf  = (unsigned short*)(ws + 21495808);
  unsigned short* abuf  = (unsigned short*)(ws + 25690112);
  float* out = (float*)d_out;

  hipLaunchKernelGGL(k_pack, dim3(96), dim3(256), 0, stream,
                     qkv_w, qkv_b, proj_w, mlp_w1, mlp_w2, wpack, bqs);
  hipLaunchKernelGGL(k_qkv, dim3(256), dim3(512), 0, stream,
                     x, ln1_g, ln1_b, wpack, bqs, qkv);
  hipLaunchKernelGGL(k_attn, dim3(32, 2, 16), dim3(256), 0, stream,
                     qkv, part_o, part_l);
  hipLaunchKernelGGL(k_reduce, dim3(2048), dim3(256), 0, stream,
                     part_o, part_l, attnb);
  hipLaunchKernelGGL(k_proj, dim3(256), dim3(512), 0, stream,
                     attnb, x, wpack, proj_b, ln2_g, ln2_b, out1, hbuf);
  hipLaunchKernelGGL(k_mlp1, dim3(256), dim3(512), 0, stream,
                     hbuf, wpack, mlp_b1, abuf);
  hipLaunchKernelGGL(k_mlp2, dim3(256), dim3(512), 0, stream,
                     abuf, wpack, mlp_b2, out1, out);
}

// Round 7
// 105.056 us; speedup vs baseline: 3.2103x; 1.0807x over previous
//
#include <hip/hip_runtime.h>
#include <hip/hip_bf16.h>
#include <math.h>

#define NSEQ   4096
#define CDIM   128
#define HD     32

typedef __attribute__((ext_vector_type(8))) short short8;
typedef __attribute__((ext_vector_type(4))) short short4v;
typedef __attribute__((ext_vector_type(4))) float f32x4;

#define QSCL (0.17677669529663687f * 1.4426950408889634f)  // 1/sqrt(32)*log2(e)

__device__ inline unsigned short f2bf(float f){
  union { float f; unsigned u; } v; v.f = f;
  return (unsigned short)((v.u + 0x7fffu + ((v.u >> 16) & 1u)) >> 16);
}
__device__ inline float bf2f(unsigned short u){
  union { unsigned u; float f; } v; v.u = ((unsigned)u) << 16;
  return v.f;
}
__device__ inline void gload_lds16(const unsigned short* g, unsigned short* l){
  __builtin_amdgcn_global_load_lds(
      (const __attribute__((address_space(1))) void*)g,
      (__attribute__((address_space(3))) void*)l, 16, 0, 0);
}

// ---- ws layout (bytes) -----------------------------------------------------
// 0        : wpack u16 [196608] (wq@0, wp@49152, w1@65536, w2@131072)
// 393216   : bqs f32 [384]
// 524288   : qkv u16 48 planes x 131072 (Q[0..15] rowmajor, Kfrag[16..31], Vfrag[32..47])
//            (reused later: attnb u16 @524288)
// 13107200 : part_ob bf16 [4][16][4096][32] (reused later: out1 f32 @13107200,
//            hbuf u16 @21495808)
// 29884416 : part_l f32 [4][16][4096] (1MB)

// ---------------- K0: pack weights to MFMA B-fragment layout ----------------
__global__ __launch_bounds__(256) void k_pack(
    const float* __restrict__ qkv_w, const float* __restrict__ qkv_b,
    const float* __restrict__ proj_w, const float* __restrict__ mlp_w1,
    const float* __restrict__ mlp_w2, unsigned short* __restrict__ wpack,
    float* __restrict__ bqs)
{
  const int gt = blockIdx.x * 256 + threadIdx.x;
  const int tile = gt >> 6, lane = gt & 63;
  const float* src; int N, KT, toff, dstoff; float scale = 1.f;
  if (tile < 96)       { src = qkv_w;  N = 384; KT = 4;  toff = tile;       dstoff = 0; }
  else if (tile < 128) { src = proj_w; N = 128; KT = 4;  toff = tile - 96;  dstoff = 49152; }
  else if (tile < 256) { src = mlp_w1; N = 512; KT = 4;  toff = tile - 128; dstoff = 65536; }
  else                 { src = mlp_w2; N = 128; KT = 16; toff = tile - 256; dstoff = 131072; }
  const int ct = toff / KT, kt = toff % KT;
  if (tile < 96 && ct < 8) scale = QSCL;   // Q columns
  const int row0 = kt * 32 + (lane >> 4) * 8, col = ct * 16 + (lane & 15);
  short8 v;
  #pragma unroll
  for (int i = 0; i < 8; i++)
    v[i] = (short)f2bf(src[(size_t)(row0 + i) * N + col] * scale);
  *(short8*)(wpack + dstoff + ((size_t)(ct * KT + kt) * 64 + lane) * 8) = v;
  if (gt < 384) bqs[gt] = qkv_b[gt] * (gt < 128 ? QSCL : 1.f);
}

// ---------------- K1: LN1 + QKV MFMA GEMM -----------------------------------
__global__ __launch_bounds__(512) void k_qkv(
    const float* __restrict__ x, const float* __restrict__ g,
    const float* __restrict__ b, const unsigned short* __restrict__ wpack,
    const float* __restrict__ bqs, unsigned short* __restrict__ qkv)
{
  __shared__ unsigned short xn[64 * 128];
  const int tid = threadIdx.x;
  const int tok0 = blockIdx.x * 64;
  {
    const int grp = tid >> 5, l = tid & 31;
    #pragma unroll
    for (int it = 0; it < 4; it++){
      const int t = it * 16 + grp;
      const float4 xv = *(const float4*)(x + (size_t)(tok0 + t) * 128 + l * 4);
      float s  = xv.x + xv.y + xv.z + xv.w;
      float s2 = xv.x*xv.x + xv.y*xv.y + xv.z*xv.z + xv.w*xv.w;
      #pragma unroll
      for (int m = 1; m <= 16; m <<= 1){ s += __shfl_xor(s, m); s2 += __shfl_xor(s2, m); }
      const float mu = s * (1.f/128.f);
      const float rs = rsqrtf(s2 * (1.f/128.f) - mu*mu + 1e-5f);
      const int e = l * 4;
      const float4 gv = *(const float4*)(g + e), bv = *(const float4*)(b + e);
      short4v pk;
      pk[0] = (short)f2bf((xv.x - mu)*rs*gv.x + bv.x);
      pk[1] = (short)f2bf((xv.y - mu)*rs*gv.y + bv.y);
      pk[2] = (short)f2bf((xv.z - mu)*rs*gv.z + bv.z);
      pk[3] = (short)f2bf((xv.w - mu)*rs*gv.w + bv.w);
      const int bl = l >> 1;
      const int slot = bl * 64 + (t & 48) + ((t & 15) ^ bl);
      *(short4v*)(xn + slot * 8 + (l & 1) * 4) = pk;
    }
  }
  __syncthreads();
  const int wv = tid >> 6, lane = tid & 63, r = lane & 15, cg = lane >> 4;
  const int rt = wv & 3, ct0 = (wv >> 2) * 12;
  short8 af[4];
  #pragma unroll
  for (int kt = 0; kt < 4; kt++){
    const int bl = kt * 4 + cg;
    const int slot = bl * 64 + rt * 16 + (r ^ bl);
    af[kt] = *(const short8*)(xn + slot * 8);
  }
  const int bidx = tok0 >> 12, nloc = (tok0 & (NSEQ - 1)) + rt * 16 + cg * 4;
  for (int ct = ct0; ct < ct0 + 12; ct++){
    f32x4 acc = {0.f, 0.f, 0.f, 0.f};
    const unsigned short* bp = wpack + ((size_t)(ct * 4) * 64 + lane) * 8;
    #pragma unroll
    for (int kt = 0; kt < 4; kt++)
      acc = __builtin_amdgcn_mfma_f32_16x16x32_bf16(af[kt], *(const short8*)(bp + kt * 512), acc, 0, 0, 0);
    const int col = ct * 16 + r;
    const float bi = bqs[col];
    if (ct < 8){                                   // Q: row-major [n][32]
      const int cc = col & 127, h = cc >> 5, d = cc & 31;
      unsigned short* plane = qkv + ((size_t)bidx * 4 + h) * (NSEQ * HD);
      #pragma unroll
      for (int reg = 0; reg < 4; reg++)
        plane[(size_t)(nloc + reg) * HD + d] = f2bf(acc[reg] + bi);
    } else if (ct < 16){                           // K: A-fragment layout per 16-row tile
      const int cc = col & 127, h = cc >> 5, d = cc & 31;
      unsigned short* plane = qkv + ((size_t)16 + bidx * 4 + h) * (NSEQ * HD);
      const int t16 = ((tok0 & (NSEQ - 1)) >> 4) + rt;
      #pragma unroll
      for (int reg = 0; reg < 4; reg++)
        plane[(size_t)t16 * 512 + (d >> 3) * 128 + (cg * 4 + reg) * 8 + (d & 7)]
            = f2bf(acc[reg] + bi);
    } else {                                       // V: PV-fragment layout
      const int vct = ct - 16, h = vct >> 1, half = vct & 1;
      unsigned short* plane = qkv + ((size_t)32 + bidx * 4 + h) * (NSEQ * HD);
      const size_t ntile = (size_t)((tok0 & (NSEQ - 1)) >> 5) + (rt >> 1);
      const size_t vo = (ntile * 2 + half) * 512 + lane * 8 + (rt & 1) * 4;
      short4v pk;
      #pragma unroll
      for (int reg = 0; reg < 4; reg++) pk[reg] = (short)f2bf(acc[reg] + bi);
      *(short4v*)(plane + vo) = pk;
    }
  }
}

// ---------------- K2: flash attention, 4-deep pipelined LDS ring ------------
// grid (32, 4, 16); block 256 (4 waves). Block: 128 q rows, chunk 1024 keys.
// LDS slot s (s=0..3): K tile at sbuf+s*2048, V tile at sbuf+s*2048+1024.
// All staging addresses are pure arithmetic -- NO private arrays (rule #20:
// a runtime-indexed pointer array spills to scratch, and scratch traffic
// increments vmcnt, silently breaking the vmcnt(2) pipeline accounting).
__global__ __launch_bounds__(256, 8) void k_attn(
    const unsigned short* __restrict__ qkv, unsigned short* __restrict__ part_ob,
    float* __restrict__ part_l)
{
  __shared__ unsigned short sbuf[8192];   // 16KB: 4 slots x (K 1KB + V 1KB)
  const int tid = threadIdx.x;
  const int lane = tid & 63, wv = tid >> 6;
  const int chunk = blockIdx.y, bh = blockIdx.z;
  const int qbase = blockIdx.x * 128 + wv * 32;
  const int kv0 = chunk * 1024;
  const unsigned short* Q  = qkv + (size_t)bh * (NSEQ * HD);
  const unsigned short* Kc = qkv + (size_t)(16 + bh) * (NSEQ * HD) + (size_t)kv0 * HD;
  const unsigned short* Vc = qkv + (size_t)(32 + bh) * (NSEQ * HD) + (size_t)kv0 * HD;
  const int r = lane & 15, cg = lane >> 4;
  const short8 qf0 = *(const short8*)(Q + (size_t)(qbase + r) * HD + cg * 8);
  const short8 qf1 = *(const short8*)(Q + (size_t)(qbase + 16 + r) * HD + cg * 8);
  // staging roles: waves 0,1 -> K halves; waves 2,3 -> V halves (1KB each)
  const unsigned short* gsrc = (wv < 2 ? Kc : Vc) + (size_t)(wv & 1) * 512 + lane * 8;
  const int dst_off = ((wv >> 1) & 1) * 1024 + (wv & 1) * 512;
  f32x4 o00 = {0.f,0.f,0.f,0.f}, o01 = {0.f,0.f,0.f,0.f};
  f32x4 o10 = {0.f,0.f,0.f,0.f}, o11 = {0.f,0.f,0.f,0.f};
  const f32x4 zero = {0.f,0.f,0.f,0.f};
  float ls0 = 0.f, ls1 = 0.f;
  // prologue: 3-deep prefetch (slots 0,1,2)
  gload_lds16(gsrc,        sbuf + 0 * 2048 + dst_off);
  gload_lds16(gsrc + 1024, sbuf + 1 * 2048 + dst_off);
  gload_lds16(gsrc + 2048, sbuf + 2 * 2048 + dst_off);
  for (int t = 0; t < 32; t++){
    // own load(t) landed (vmcnt(2): exactly 3 loads outstanding by
    // construction) AND own prior-iter LDS reads done (lgkmcnt(0))
    // BEFORE signaling barrier arrival; then slot rotation is race-free.
    asm volatile("s_waitcnt vmcnt(2) lgkmcnt(0)" ::: "memory");
    __builtin_amdgcn_sched_barrier(0);
    __builtin_amdgcn_s_barrier();
    __builtin_amdgcn_sched_barrier(0);
    const int tn = (t + 3 > 31) ? 31 : t + 3;   // clamped dummy keeps vmcnt uniform
    gload_lds16(gsrc + (size_t)tn * 1024, sbuf + ((t + 3) & 3) * 2048 + dst_off);
    const unsigned short* skb = sbuf + (t & 3) * 2048;
    const unsigned short* svb = skb + 1024;
    const short8 ka0 = *(const short8*)(skb + lane * 8);
    const short8 ka1 = *(const short8*)(skb + 512 + lane * 8);
    const short8 va0 = *(const short8*)(svb + lane * 8);
    const short8 va1 = *(const short8*)(svb + 512 + lane * 8);
    const f32x4 s00 = __builtin_amdgcn_mfma_f32_16x16x32_bf16(ka0, qf0, zero, 0, 0, 0);
    const f32x4 s01 = __builtin_amdgcn_mfma_f32_16x16x32_bf16(ka1, qf0, zero, 0, 0, 0);
    const f32x4 s10 = __builtin_amdgcn_mfma_f32_16x16x32_bf16(ka0, qf1, zero, 0, 0, 0);
    const f32x4 s11 = __builtin_amdgcn_mfma_f32_16x16x32_bf16(ka1, qf1, zero, 0, 0, 0);
    float p00[4], p01[4], p10[4], p11[4];
    #pragma unroll
    for (int i = 0; i < 4; i++){
      p00[i] = __builtin_amdgcn_exp2f(s00[i]);
      p01[i] = __builtin_amdgcn_exp2f(s01[i]);
      p10[i] = __builtin_amdgcn_exp2f(s10[i]);
      p11[i] = __builtin_amdgcn_exp2f(s11[i]);
      ls0 += p00[i] + p01[i];
      ls1 += p10[i] + p11[i];
    }
    unsigned c0, c1, c2, c3, c4, c5, c6, c7;
    asm("v_cvt_pk_bf16_f32 %0, %1, %2" : "=v"(c0) : "v"(p00[0]), "v"(p00[1]));
    asm("v_cvt_pk_bf16_f32 %0, %1, %2" : "=v"(c1) : "v"(p00[2]), "v"(p00[3]));
    asm("v_cvt_pk_bf16_f32 %0, %1, %2" : "=v"(c2) : "v"(p01[0]), "v"(p01[1]));
    asm("v_cvt_pk_bf16_f32 %0, %1, %2" : "=v"(c3) : "v"(p01[2]), "v"(p01[3]));
    asm("v_cvt_pk_bf16_f32 %0, %1, %2" : "=v"(c4) : "v"(p10[0]), "v"(p10[1]));
    asm("v_cvt_pk_bf16_f32 %0, %1, %2" : "=v"(c5) : "v"(p10[2]), "v"(p10[3]));
    asm("v_cvt_pk_bf16_f32 %0, %1, %2" : "=v"(c6) : "v"(p11[0]), "v"(p11[1]));
    asm("v_cvt_pk_bf16_f32 %0, %1, %2" : "=v"(c7) : "v"(p11[2]), "v"(p11[3]));
    union { unsigned u[4]; short8 s; } pa, pb;
    pa.u[0] = c0; pa.u[1] = c1; pa.u[2] = c2; pa.u[3] = c3;
    pb.u[0] = c4; pb.u[1] = c5; pb.u[2] = c6; pb.u[3] = c7;
    o00 = __builtin_amdgcn_mfma_f32_16x16x32_bf16(va0, pa.s, o00, 0, 0, 0);
    o01 = __builtin_amdgcn_mfma_f32_16x16x32_bf16(va1, pa.s, o01, 0, 0, 0);
    o10 = __builtin_amdgcn_mfma_f32_16x16x32_bf16(va0, pb.s, o10, 0, 0, 0);
    o11 = __builtin_amdgcn_mfma_f32_16x16x32_bf16(va1, pb.s, o11, 0, 0, 0);
  }
  // drain trailing dummy LDS-DMA writes before workgroup exit -- otherwise
  // they can land in a NEW block's LDS after this one retires.
  asm volatile("s_waitcnt vmcnt(0)" ::: "memory");
  ls0 += __shfl_xor(ls0, 16); ls0 += __shfl_xor(ls0, 32);
  ls1 += __shfl_xor(ls1, 16); ls1 += __shfl_xor(ls1, 32);
  unsigned short* po = part_ob + (((size_t)(chunk * 16 + bh) * NSEQ) + qbase + r) * HD;
  short4v w0, w1, w2, w3;
  #pragma unroll
  for (int j = 0; j < 4; j++){
    w0[j] = (short)f2bf(o00[j]); w1[j] = (short)f2bf(o01[j]);
    w2[j] = (short)f2bf(o10[j]); w3[j] = (short)f2bf(o11[j]);
  }
  *(short4v*)(po + cg * 4)              = w0;
  *(short4v*)(po + 16 + cg * 4)         = w1;
  *(short4v*)(po + 16 * HD + cg * 4)    = w2;
  *(short4v*)(po + 16 * HD + 16 + cg * 4) = w3;
  if (lane < 16){
    part_l[(size_t)(chunk * 16 + bh) * NSEQ + qbase + r] = ls0;
    part_l[(size_t)(chunk * 16 + bh) * NSEQ + qbase + 16 + r] = ls1;
  }
}

// ---------------- K3: combine partials -> attn bf16 [16384][128] ------------
__global__ __launch_bounds__(256) void k_reduce(
    const unsigned short* __restrict__ part_ob, const float* __restrict__ part_l,
    unsigned short* __restrict__ attnb)
{
  const int gt = blockIdx.x * 256 + threadIdx.x;
  const int j = gt >> 3, d0 = (gt & 7) * 4;
  const int q = j & (NSEQ - 1), bh = j >> 12;
  float s0 = 0.f, s1 = 0.f, s2 = 0.f, s3 = 0.f;
  float lsum = 0.f;
  #pragma unroll
  for (int c = 0; c < 4; c++){
    const short4v v = *(const short4v*)(part_ob + (((size_t)(c * 16 + bh) * NSEQ) + q) * HD + d0);
    s0 += bf2f((unsigned short)v[0]); s1 += bf2f((unsigned short)v[1]);
    s2 += bf2f((unsigned short)v[2]); s3 += bf2f((unsigned short)v[3]);
    lsum += part_l[(size_t)(c * 16 + bh) * NSEQ + q];
  }
  const float inv = 1.f / lsum;
  short4v pk;
  pk[0] = (short)f2bf(s0 * inv); pk[1] = (short)f2bf(s1 * inv);
  pk[2] = (short)f2bf(s2 * inv); pk[3] = (short)f2bf(s3 * inv);
  *(short4v*)(attnb + ((size_t)(bh >> 2) * NSEQ + q) * CDIM + (bh & 3) * HD + d0) = pk;
}

// ---------------- K4: proj MFMA + bias + residual -> out1 ; LN2 -> h --------
__global__ __launch_bounds__(512) void k_proj(
    const unsigned short* __restrict__ attnb, const float* __restrict__ x,
    const unsigned short* __restrict__ wpack, const float* __restrict__ pb,
    const float* __restrict__ g2, const float* __restrict__ b2,
    float* __restrict__ out1, unsigned short* __restrict__ h)
{
  __shared__ float sb[64 * 128];
  const int tid = threadIdx.x;
  const int tok0 = blockIdx.x * 64;
  const int wv = tid >> 6, lane = tid & 63, r = lane & 15, cg = lane >> 4;
  const int rt = wv & 3, ct0 = (wv >> 2) * 4;
  short8 af[4];
  #pragma unroll
  for (int kt = 0; kt < 4; kt++)
    af[kt] = *(const short8*)(attnb + (size_t)(tok0 + rt * 16 + r) * CDIM + kt * 32 + cg * 8);
  const unsigned short* wp = wpack + 49152;
  for (int ct = ct0; ct < ct0 + 4; ct++){
    f32x4 acc = {0.f, 0.f, 0.f, 0.f};
    const unsigned short* bp = wp + ((size_t)(ct * 4) * 64 + lane) * 8;
    #pragma unroll
    for (int kt = 0; kt < 4; kt++)
      acc = __builtin_amdgcn_mfma_f32_16x16x32_bf16(af[kt], *(const short8*)(bp + kt * 512), acc, 0, 0, 0);
    const int col = ct * 16 + r;
    const float bi = pb[col];
    #pragma unroll
    for (int reg = 0; reg < 4; reg++){
      const int tl = rt * 16 + cg * 4 + reg;
      sb[tl * 128 + col] = acc[reg] + bi + x[(size_t)(tok0 + tl) * 128 + col];
    }
  }
  __syncthreads();
  {
    const int grp = tid >> 5, l = tid & 31;
    #pragma unroll
    for (int it = 0; it < 4; it++){
      const int t = it * 16 + grp;
      const float4 xv = *(const float4*)(sb + t * 128 + l * 4);
      float s  = xv.x + xv.y + xv.z + xv.w;
      float s2 = xv.x*xv.x + xv.y*xv.y + xv.z*xv.z + xv.w*xv.w;
      #pragma unroll
      for (int m = 1; m <= 16; m <<= 1){ s += __shfl_xor(s, m); s2 += __shfl_xor(s2, m); }
      const float mu = s * (1.f/128.f);
      const float rs = rsqrtf(s2 * (1.f/128.f) - mu*mu + 1e-5f);
      const int e = l * 4;
      *(float4*)(out1 + (size_t)(tok0 + t) * 128 + e) = xv;
      const float4 gv = *(const float4*)(g2 + e), bv = *(const float4*)(b2 + e);
      short4v pk;
      pk[0] = (short)f2bf((xv.x - mu)*rs*gv.x + bv.x);
      pk[1] = (short)f2bf((xv.y - mu)*rs*gv.y + bv.y);
      pk[2] = (short)f2bf((xv.z - mu)*rs*gv.z + bv.z);
      pk[3] = (short)f2bf((xv.w - mu)*rs*gv.w + bv.w);
      *(short4v*)(h + (size_t)(tok0 + t) * 128 + e) = pk;
    }
  }
}

// ---------------- K5: fused MLP1 + GELU + MLP2 + residual -------------------
// block: 64 tokens, 512 threads; activation tile lives in LDS (fragment layout)
__global__ __launch_bounds__(512, 4) void k_mlp(
    const unsigned short* __restrict__ h, const unsigned short* __restrict__ wpack,
    const float* __restrict__ b1, const float* __restrict__ b2p,
    const float* __restrict__ out1, float* __restrict__ out)
{
  __shared__ unsigned short afrag[4][8192];   // 64KB: [row-tile][g*128 + rr*8 + i]
  const int tid = threadIdx.x, tok0 = blockIdx.x * 64;
  const int wv = tid >> 6, lane = tid & 63, r = lane & 15, cg = lane >> 4;
  const int rt = wv & 3;
  { // phase 1: a = GELU(h @ w1 + b1), cols [ct0*16, ct0*16+256)
    const int ct0 = (wv >> 2) * 16;
    short8 af[4];
    #pragma unroll
    for (int kt = 0; kt < 4; kt++)
      af[kt] = *(const short8*)(h + (size_t)(tok0 + rt * 16 + r) * CDIM + kt * 32 + cg * 8);
    const unsigned short* w1 = wpack + 65536;
    for (int ct = ct0; ct < ct0 + 16; ct++){
      f32x4 acc = {0.f, 0.f, 0.f, 0.f};
      const unsigned short* bp = w1 + ((size_t)(ct * 4) * 64 + lane) * 8;
      #pragma unroll
      for (int kt = 0; kt < 4; kt++)
        acc = __builtin_amdgcn_mfma_f32_16x16x32_bf16(af[kt], *(const short8*)(bp + kt * 512), acc, 0, 0, 0);
      const int col = ct * 16 + r;
      const float bi = b1[col];
      const int gidx = (col >> 3), i = col & 7;
      #pragma unroll
      for (int reg = 0; reg < 4; reg++){
        const float v = acc[reg] + bi;
        const float ge = 0.5f * v * (1.f + erff(v * 0.70710678118f));
        afrag[rt][gidx * 128 + (cg * 4 + reg) * 8 + i] = f2bf(ge);
      }
    }
  }
  __syncthreads();
  { // phase 2: out = a @ w2 + b2 + out1
    const int ct0 = (wv >> 2) * 4;
    const unsigned short* w2 = wpack + 131072;
    f32x4 acc[4] = {{0.f,0.f,0.f,0.f},{0.f,0.f,0.f,0.f},{0.f,0.f,0.f,0.f},{0.f,0.f,0.f,0.f}};
    for (int kt = 0; kt < 16; kt++){
      const short8 af = *(const short8*)(&afrag[rt][(kt * 4 + cg) * 128 + r * 8]);
      #pragma unroll
      for (int c = 0; c < 4; c++){
        const unsigned short* bp = w2 + ((size_t)((ct0 + c) * 16 + kt) * 64 + lane) * 8;
        acc[c] = __builtin_amdgcn_mfma_f32_16x16x32_bf16(af, *(const short8*)(bp), acc[c], 0, 0, 0);
      }
    }
    #pragma unroll
    for (int c = 0; c < 4; c++){
      const int col = (ct0 + c) * 16 + r;
      const float bi = b2p[col];
      #pragma unroll
      for (int reg = 0; reg < 4; reg++){
        const size_t n = tok0 + rt * 16 + cg * 4 + reg;
        out[n * 128 + col] = acc[c][reg] + bi + out1[n * 128 + col];
      }
    }
  }
}

extern "C" void kernel_launch(void* const* d_in, const int* in_sizes, int n_in,
                              void* d_out, int out_size, void* d_ws, size_t ws_size,
                              hipStream_t stream)
{
  const float* x      = (const float*)d_in[0];
  const float* ln1_g  = (const float*)d_in[1];
  const float* ln1_b  = (const float*)d_in[2];
  const float* qkv_w  = (const float*)d_in[3];
  const float* qkv_b  = (const float*)d_in[4];
  const float* proj_w = (const float*)d_in[5];
  const float* proj_b = (const float*)d_in[6];
  const float* ln2_g  = (const float*)d_in[7];
  const float* ln2_b  = (const float*)d_in[8];
  const float* mlp_w1 = (const float*)d_in[9];
  const float* mlp_b1 = (const float*)d_in[10];
  const float* mlp_w2 = (const float*)d_in[11];
  const float* mlp_b2 = (const float*)d_in[12];

  char* ws = (char*)d_ws;
  unsigned short* wpack  = (unsigned short*)(ws);
  float*          bqs    = (float*)(ws + 393216);
  unsigned short* qkv    = (unsigned short*)(ws + 524288);
  unsigned short* attnb  = (unsigned short*)(ws + 524288);     // reuses qkv region
  unsigned short* part_ob = (unsigned short*)(ws + 13107200);
  float*          part_l = (float*)(ws + 29884416);
  float*          out1   = (float*)(ws + 13107200);            // reuses part_ob region
  unsigned short* hbuf   = (unsigned short*)(ws + 21495808);
  float* out = (float*)d_out;

  hipLaunchKernelGGL(k_pack, dim3(96), dim3(256), 0, stream,
                     qkv_w, qkv_b, proj_w, mlp_w1, mlp_w2, wpack, bqs);
  hipLaunchKernelGGL(k_qkv, dim3(256), dim3(512), 0, stream,
                     x, ln1_g, ln1_b, wpack, bqs, qkv);
  hipLaunchKernelGGL(k_attn, dim3(32, 4, 16), dim3(256), 0, stream,
                     qkv, part_ob, part_l);
  hipLaunchKernelGGL(k_reduce, dim3(2048), dim3(256), 0, stream,
                     part_ob, part_l, attnb);
  hipLaunchKernelGGL(k_proj, dim3(256), dim3(512), 0, stream,
                     attnb, x, wpack, proj_b, ln2_g, ln2_b, out1, hbuf);
  hipLaunchKernelGGL(k_mlp, dim3(256), dim3(512), 0, stream,
                     hbuf, wpack, mlp_b1, mlp_b2, out1, out);
}

// Round 8
// 89.533 us; speedup vs baseline: 3.7669x; 1.1734x over previous
//
#include <hip/hip_runtime.h>
#include <hip/hip_bf16.h>
#include <math.h>

#define NSEQ   4096
#define CDIM   128
#define HD     32

typedef __attribute__((ext_vector_type(8))) short short8;
typedef __attribute__((ext_vector_type(4))) short short4v;
typedef __attribute__((ext_vector_type(4))) float f32x4;

#define QSCL (0.17677669529663687f * 1.4426950408889634f)  // 1/sqrt(32)*log2(e)

__device__ inline unsigned short f2bf(float f){
  union { float f; unsigned u; } v; v.f = f;
  return (unsigned short)((v.u + 0x7fffu + ((v.u >> 16) & 1u)) >> 16);
}
__device__ inline float bf2f(unsigned short u){
  union { unsigned u; float f; } v; v.u = ((unsigned)u) << 16;
  return v.f;
}
__device__ inline void gload_lds16(const unsigned short* g, unsigned short* l){
  __builtin_amdgcn_global_load_lds(
      (const __attribute__((address_space(1))) void*)g,
      (__attribute__((address_space(3))) void*)l, 16, 0, 0);
}

// ---- ws layout (bytes) -----------------------------------------------------
// 0        : wpack u16 [196608] (wq@0, wp@49152, w1@65536, w2@131072)
// 393216   : bqs f32 [384]
// 524288   : qkv u16 48 planes x 131072 (Q[0..15] rowmajor, Kfrag[16..31], Vfrag[32..47])
// 13107200 : part_ob bf16 [4][16][4096][32]
// 29884416 : part_l f32 [4][16][4096] (1MB)

// ---------------- K0: pack weights to MFMA B-fragment layout ----------------
__global__ __launch_bounds__(256) void k_pack(
    const float* __restrict__ qkv_w, const float* __restrict__ qkv_b,
    const float* __restrict__ proj_w, const float* __restrict__ mlp_w1,
    const float* __restrict__ mlp_w2, unsigned short* __restrict__ wpack,
    float* __restrict__ bqs)
{
  const int gt = blockIdx.x * 256 + threadIdx.x;
  const int tile = gt >> 6, lane = gt & 63;
  const float* src; int N, KT, toff, dstoff; float scale = 1.f;
  if (tile < 96)       { src = qkv_w;  N = 384; KT = 4;  toff = tile;       dstoff = 0; }
  else if (tile < 128) { src = proj_w; N = 128; KT = 4;  toff = tile - 96;  dstoff = 49152; }
  else if (tile < 256) { src = mlp_w1; N = 512; KT = 4;  toff = tile - 128; dstoff = 65536; }
  else                 { src = mlp_w2; N = 128; KT = 16; toff = tile - 256; dstoff = 131072; }
  const int ct = toff / KT, kt = toff % KT;
  if (tile < 96 && ct < 8) scale = QSCL;   // Q columns
  const int row0 = kt * 32 + (lane >> 4) * 8, col = ct * 16 + (lane & 15);
  short8 v;
  #pragma unroll
  for (int i = 0; i < 8; i++)
    v[i] = (short)f2bf(src[(size_t)(row0 + i) * N + col] * scale);
  *(short8*)(wpack + dstoff + ((size_t)(ct * KT + kt) * 64 + lane) * 8) = v;
  if (gt < 384) bqs[gt] = qkv_b[gt] * (gt < 128 ? QSCL : 1.f);
}

// ---------------- K1: LN1 + QKV MFMA GEMM -----------------------------------
__global__ __launch_bounds__(512) void k_qkv(
    const float* __restrict__ x, const float* __restrict__ g,
    const float* __restrict__ b, const unsigned short* __restrict__ wpack,
    const float* __restrict__ bqs, unsigned short* __restrict__ qkv)
{
  __shared__ unsigned short xn[64 * 128];
  const int tid = threadIdx.x;
  const int tok0 = blockIdx.x * 64;
  {
    const int grp = tid >> 5, l = tid & 31;
    #pragma unroll
    for (int it = 0; it < 4; it++){
      const int t = it * 16 + grp;
      const float4 xv = *(const float4*)(x + (size_t)(tok0 + t) * 128 + l * 4);
      float s  = xv.x + xv.y + xv.z + xv.w;
      float s2 = xv.x*xv.x + xv.y*xv.y + xv.z*xv.z + xv.w*xv.w;
      #pragma unroll
      for (int m = 1; m <= 16; m <<= 1){ s += __shfl_xor(s, m); s2 += __shfl_xor(s2, m); }
      const float mu = s * (1.f/128.f);
      const float rs = rsqrtf(s2 * (1.f/128.f) - mu*mu + 1e-5f);
      const int e = l * 4;
      const float4 gv = *(const float4*)(g + e), bv = *(const float4*)(b + e);
      short4v pk;
      pk[0] = (short)f2bf((xv.x - mu)*rs*gv.x + bv.x);
      pk[1] = (short)f2bf((xv.y - mu)*rs*gv.y + bv.y);
      pk[2] = (short)f2bf((xv.z - mu)*rs*gv.z + bv.z);
      pk[3] = (short)f2bf((xv.w - mu)*rs*gv.w + bv.w);
      const int bl = l >> 1;
      const int slot = bl * 64 + (t & 48) + ((t & 15) ^ bl);
      *(short4v*)(xn + slot * 8 + (l & 1) * 4) = pk;
    }
  }
  __syncthreads();
  const int wv = tid >> 6, lane = tid & 63, r = lane & 15, cg = lane >> 4;
  const int rt = wv & 3, ct0 = (wv >> 2) * 12;
  short8 af[4];
  #pragma unroll
  for (int kt = 0; kt < 4; kt++){
    const int bl = kt * 4 + cg;
    const int slot = bl * 64 + rt * 16 + (r ^ bl);
    af[kt] = *(const short8*)(xn + slot * 8);
  }
  const int bidx = tok0 >> 12, nloc = (tok0 & (NSEQ - 1)) + rt * 16 + cg * 4;
  for (int ct = ct0; ct < ct0 + 12; ct++){
    f32x4 acc = {0.f, 0.f, 0.f, 0.f};
    const unsigned short* bp = wpack + ((size_t)(ct * 4) * 64 + lane) * 8;
    #pragma unroll
    for (int kt = 0; kt < 4; kt++)
      acc = __builtin_amdgcn_mfma_f32_16x16x32_bf16(af[kt], *(const short8*)(bp + kt * 512), acc, 0, 0, 0);
    const int col = ct * 16 + r;
    const float bi = bqs[col];
    if (ct < 8){                                   // Q: row-major [n][32]
      const int cc = col & 127, h = cc >> 5, d = cc & 31;
      unsigned short* plane = qkv + ((size_t)bidx * 4 + h) * (NSEQ * HD);
      #pragma unroll
      for (int reg = 0; reg < 4; reg++)
        plane[(size_t)(nloc + reg) * HD + d] = f2bf(acc[reg] + bi);
    } else if (ct < 16){                           // K: A-fragment layout per 16-row tile
      const int cc = col & 127, h = cc >> 5, d = cc & 31;
      unsigned short* plane = qkv + ((size_t)16 + bidx * 4 + h) * (NSEQ * HD);
      const int t16 = ((tok0 & (NSEQ - 1)) >> 4) + rt;
      #pragma unroll
      for (int reg = 0; reg < 4; reg++)
        plane[(size_t)t16 * 512 + (d >> 3) * 128 + (cg * 4 + reg) * 8 + (d & 7)]
            = f2bf(acc[reg] + bi);
    } else {                                       // V: PV-fragment layout
      const int vct = ct - 16, h = vct >> 1, half = vct & 1;
      unsigned short* plane = qkv + ((size_t)32 + bidx * 4 + h) * (NSEQ * HD);
      const size_t ntile = (size_t)((tok0 & (NSEQ - 1)) >> 5) + (rt >> 1);
      const size_t vo = (ntile * 2 + half) * 512 + lane * 8 + (rt & 1) * 4;
      short4v pk;
      #pragma unroll
      for (int reg = 0; reg < 4; reg++) pk[reg] = (short)f2bf(acc[reg] + bi);
      *(short4v*)(plane + vo) = pk;
    }
  }
}

// ---------------- K2: flash attention, 4-deep pipelined LDS ring ------------
// grid (32, 4, 16); block 256 (4 waves). Block: 128 q rows, chunk 1024 keys.
// lsum via ones-MFMA: D[m][q] = sum_k P[k][q] on the (less busy) MFMA pipe,
// replacing 16 VALU adds/iter + the end shuffles.
__global__ __launch_bounds__(256, 8) void k_attn(
    const unsigned short* __restrict__ qkv, unsigned short* __restrict__ part_ob,
    float* __restrict__ part_l)
{
  __shared__ unsigned short sbuf[8192];   // 16KB: 4 slots x (K 1KB + V 1KB)
  const int tid = threadIdx.x;
  const int lane = tid & 63, wv = tid >> 6;
  const int chunk = blockIdx.y, bh = blockIdx.z;
  const int qbase = blockIdx.x * 128 + wv * 32;
  const int kv0 = chunk * 1024;
  const unsigned short* Q  = qkv + (size_t)bh * (NSEQ * HD);
  const unsigned short* Kc = qkv + (size_t)(16 + bh) * (NSEQ * HD) + (size_t)kv0 * HD;
  const unsigned short* Vc = qkv + (size_t)(32 + bh) * (NSEQ * HD) + (size_t)kv0 * HD;
  const int r = lane & 15, cg = lane >> 4;
  const short8 qf0 = *(const short8*)(Q + (size_t)(qbase + r) * HD + cg * 8);
  const short8 qf1 = *(const short8*)(Q + (size_t)(qbase + 16 + r) * HD + cg * 8);
  const unsigned short* gsrc = (wv < 2 ? Kc : Vc) + (size_t)(wv & 1) * 512 + lane * 8;
  const int dst_off = ((wv >> 1) & 1) * 1024 + (wv & 1) * 512;
  union { unsigned u[4]; short8 s; } onesu;
  onesu.u[0] = 0x3F803F80u; onesu.u[1] = 0x3F803F80u;
  onesu.u[2] = 0x3F803F80u; onesu.u[3] = 0x3F803F80u;
  const short8 vones = onesu.s;
  f32x4 o00 = {0.f,0.f,0.f,0.f}, o01 = {0.f,0.f,0.f,0.f};
  f32x4 o10 = {0.f,0.f,0.f,0.f}, o11 = {0.f,0.f,0.f,0.f};
  f32x4 lacc0 = {0.f,0.f,0.f,0.f}, lacc1 = {0.f,0.f,0.f,0.f};
  const f32x4 zero = {0.f,0.f,0.f,0.f};
  // prologue: 3-deep prefetch (slots 0,1,2)
  gload_lds16(gsrc,        sbuf + 0 * 2048 + dst_off);
  gload_lds16(gsrc + 1024, sbuf + 1 * 2048 + dst_off);
  gload_lds16(gsrc + 2048, sbuf + 2 * 2048 + dst_off);
  for (int t = 0; t < 32; t++){
    asm volatile("s_waitcnt vmcnt(2) lgkmcnt(0)" ::: "memory");
    __builtin_amdgcn_sched_barrier(0);
    __builtin_amdgcn_s_barrier();
    __builtin_amdgcn_sched_barrier(0);
    const int tn = (t + 3 > 31) ? 31 : t + 3;   // clamped dummy keeps vmcnt uniform
    gload_lds16(gsrc + (size_t)tn * 1024, sbuf + ((t + 3) & 3) * 2048 + dst_off);
    const unsigned short* skb = sbuf + (t & 3) * 2048;
    const unsigned short* svb = skb + 1024;
    const short8 ka0 = *(const short8*)(skb + lane * 8);
    const short8 ka1 = *(const short8*)(skb + 512 + lane * 8);
    const short8 va0 = *(const short8*)(svb + lane * 8);
    const short8 va1 = *(const short8*)(svb + 512 + lane * 8);
    const f32x4 s00 = __builtin_amdgcn_mfma_f32_16x16x32_bf16(ka0, qf0, zero, 0, 0, 0);
    const f32x4 s01 = __builtin_amdgcn_mfma_f32_16x16x32_bf16(ka1, qf0, zero, 0, 0, 0);
    const f32x4 s10 = __builtin_amdgcn_mfma_f32_16x16x32_bf16(ka0, qf1, zero, 0, 0, 0);
    const f32x4 s11 = __builtin_amdgcn_mfma_f32_16x16x32_bf16(ka1, qf1, zero, 0, 0, 0);
    float p00[4], p01[4], p10[4], p11[4];
    #pragma unroll
    for (int i = 0; i < 4; i++){
      p00[i] = __builtin_amdgcn_exp2f(s00[i]);
      p01[i] = __builtin_amdgcn_exp2f(s01[i]);
      p10[i] = __builtin_amdgcn_exp2f(s10[i]);
      p11[i] = __builtin_amdgcn_exp2f(s11[i]);
    }
    unsigned c0, c1, c2, c3, c4, c5, c6, c7;
    asm("v_cvt_pk_bf16_f32 %0, %1, %2" : "=v"(c0) : "v"(p00[0]), "v"(p00[1]));
    asm("v_cvt_pk_bf16_f32 %0, %1, %2" : "=v"(c1) : "v"(p00[2]), "v"(p00[3]));
    asm("v_cvt_pk_bf16_f32 %0, %1, %2" : "=v"(c2) : "v"(p01[0]), "v"(p01[1]));
    asm("v_cvt_pk_bf16_f32 %0, %1, %2" : "=v"(c3) : "v"(p01[2]), "v"(p01[3]));
    asm("v_cvt_pk_bf16_f32 %0, %1, %2" : "=v"(c4) : "v"(p10[0]), "v"(p10[1]));
    asm("v_cvt_pk_bf16_f32 %0, %1, %2" : "=v"(c5) : "v"(p10[2]), "v"(p10[3]));
    asm("v_cvt_pk_bf16_f32 %0, %1, %2" : "=v"(c6) : "v"(p11[0]), "v"(p11[1]));
    asm("v_cvt_pk_bf16_f32 %0, %1, %2" : "=v"(c7) : "v"(p11[2]), "v"(p11[3]));
    union { unsigned u[4]; short8 s; } pa, pb;
    pa.u[0] = c0; pa.u[1] = c1; pa.u[2] = c2; pa.u[3] = c3;
    pb.u[0] = c4; pb.u[1] = c5; pb.u[2] = c6; pb.u[3] = c7;
    o00 = __builtin_amdgcn_mfma_f32_16x16x32_bf16(va0, pa.s, o00, 0, 0, 0);
    o01 = __builtin_amdgcn_mfma_f32_16x16x32_bf16(va1, pa.s, o01, 0, 0, 0);
    o10 = __builtin_amdgcn_mfma_f32_16x16x32_bf16(va0, pb.s, o10, 0, 0, 0);
    o11 = __builtin_amdgcn_mfma_f32_16x16x32_bf16(va1, pb.s, o11, 0, 0, 0);
    lacc0 = __builtin_amdgcn_mfma_f32_16x16x32_bf16(vones, pa.s, lacc0, 0, 0, 0);
    lacc1 = __builtin_amdgcn_mfma_f32_16x16x32_bf16(vones, pb.s, lacc1, 0, 0, 0);
  }
  // drain trailing dummy LDS-DMA writes before workgroup exit
  asm volatile("s_waitcnt vmcnt(0)" ::: "memory");
  const float ls0 = lacc0[0], ls1 = lacc1[0];   // all regs/lane-groups equal
  unsigned short* po = part_ob + (((size_t)(chunk * 16 + bh) * NSEQ) + qbase + r) * HD;
  short4v w0, w1, w2, w3;
  #pragma unroll
  for (int j = 0; j < 4; j++){
    w0[j] = (short)f2bf(o00[j]); w1[j] = (short)f2bf(o01[j]);
    w2[j] = (short)f2bf(o10[j]); w3[j] = (short)f2bf(o11[j]);
  }
  *(short4v*)(po + cg * 4)              = w0;
  *(short4v*)(po + 16 + cg * 4)         = w1;
  *(short4v*)(po + 16 * HD + cg * 4)    = w2;
  *(short4v*)(po + 16 * HD + 16 + cg * 4) = w3;
  if (lane < 16){
    part_l[(size_t)(chunk * 16 + bh) * NSEQ + qbase + r] = ls0;
    part_l[(size_t)(chunk * 16 + bh) * NSEQ + qbase + 16 + r] = ls1;
  }
}

// ---------------- K3: fused reduce + proj + LN2 + MLP1 + GELU + MLP2 --------
// block: 32 tokens, 512 threads (8 waves: rt = wv&1, cgp = wv>>1).
// LDS 56KB -> 2 blocks/CU. Residual and activations never touch global.
__global__ __launch_bounds__(512, 2) void k_fused(
    const unsigned short* __restrict__ part_ob, const float* __restrict__ part_l,
    const float* __restrict__ x, const unsigned short* __restrict__ wpack,
    const float* __restrict__ pb, const float* __restrict__ g2,
    const float* __restrict__ b2, const float* __restrict__ b1,
    const float* __restrict__ b2m, float* __restrict__ out)
{
  __shared__ float sb[32 * 128];             // 16KB residual (x + attn@proj)
  __shared__ unsigned short hfr[2][2048];    //  8KB LN2 output, A-frag layout
  __shared__ unsigned short afr[2][8192];    // 32KB GELU acts, A-frag layout
  const int tid = threadIdx.x, tok0 = blockIdx.x * 32;
  const int wv = tid >> 6, lane = tid & 63, r = lane & 15, cg = lane >> 4;
  const int rt = wv & 1, cgp = wv >> 1;
  const int bidx = tok0 >> 12, qn0 = (tok0 & (NSEQ - 1)) + rt * 16 + r;
  // ---- phase A: fused softmax-reduce -> proj A-frag; proj MFMA; residual
  short8 af[4];
  #pragma unroll
  for (int kt = 0; kt < 4; kt++){
    const int bh = bidx * 4 + kt;
    float s8[8] = {0.f,0.f,0.f,0.f,0.f,0.f,0.f,0.f};
    float lsum = 0.f;
    #pragma unroll
    for (int c = 0; c < 4; c++){
      const short8 v = *(const short8*)(part_ob +
          (((size_t)(c * 16 + bh) * NSEQ) + qn0) * HD + cg * 8);
      #pragma unroll
      for (int i = 0; i < 8; i++) s8[i] += bf2f((unsigned short)v[i]);
      lsum += part_l[(size_t)(c * 16 + bh) * NSEQ + qn0];
    }
    const float inv = 1.f / lsum;
    #pragma unroll
    for (int i = 0; i < 8; i++) af[kt][i] = (short)f2bf(s8[i] * inv);
  }
  {
    const unsigned short* wp = wpack + 49152;
    for (int ct = cgp * 2; ct < cgp * 2 + 2; ct++){
      f32x4 acc = {0.f, 0.f, 0.f, 0.f};
      const unsigned short* bp = wp + ((size_t)(ct * 4) * 64 + lane) * 8;
      #pragma unroll
      for (int kt = 0; kt < 4; kt++)
        acc = __builtin_amdgcn_mfma_f32_16x16x32_bf16(af[kt], *(const short8*)(bp + kt * 512), acc, 0, 0, 0);
      const int col = ct * 16 + r;
      const float bi = pb[col];
      #pragma unroll
      for (int reg = 0; reg < 4; reg++){
        const int tl = rt * 16 + cg * 4 + reg;
        sb[tl * 128 + col] = acc[reg] + bi + x[(size_t)(tok0 + tl) * 128 + col];
      }
    }
  }
  __syncthreads();
  // ---- phase B: LN2 -> hfr (A-fragment layout in LDS)
  {
    const int grp = tid >> 5, l = tid & 31;
    #pragma unroll
    for (int it = 0; it < 2; it++){
      const int t = it * 16 + grp;
      const float4 xv = *(const float4*)(sb + t * 128 + l * 4);
      float s  = xv.x + xv.y + xv.z + xv.w;
      float s2 = xv.x*xv.x + xv.y*xv.y + xv.z*xv.z + xv.w*xv.w;
      #pragma unroll
      for (int m = 1; m <= 16; m <<= 1){ s += __shfl_xor(s, m); s2 += __shfl_xor(s2, m); }
      const float mu = s * (1.f/128.f);
      const float rs = rsqrtf(s2 * (1.f/128.f) - mu*mu + 1e-5f);
      const int e = l * 4;
      const float4 gv = *(const float4*)(g2 + e), bv = *(const float4*)(b2 + e);
      short4v pk;
      pk[0] = (short)f2bf((xv.x - mu)*rs*gv.x + bv.x);
      pk[1] = (short)f2bf((xv.y - mu)*rs*gv.y + bv.y);
      pk[2] = (short)f2bf((xv.z - mu)*rs*gv.z + bv.z);
      pk[3] = (short)f2bf((xv.w - mu)*rs*gv.w + bv.w);
      // element (t, e+j) -> frag pos (e>>3)*128 + (t&15)*8 + (e&7)+j
      *(short4v*)(&hfr[t >> 4][(e >> 3) * 128 + (t & 15) * 8 + (e & 7)]) = pk;
    }
  }
  __syncthreads();
  // ---- phase C: MLP1 + GELU -> afr (A-fragment layout)
  {
    short8 hf[4];
    #pragma unroll
    for (int kt = 0; kt < 4; kt++)
      hf[kt] = *(const short8*)(&hfr[rt][(kt * 4 + cg) * 128 + r * 8]);
    const unsigned short* w1 = wpack + 65536;
    for (int ct = cgp * 8; ct < cgp * 8 + 8; ct++){
      f32x4 acc = {0.f, 0.f, 0.f, 0.f};
      const unsigned short* bp = w1 + ((size_t)(ct * 4) * 64 + lane) * 8;
      #pragma unroll
      for (int kt = 0; kt < 4; kt++)
        acc = __builtin_amdgcn_mfma_f32_16x16x32_bf16(hf[kt], *(const short8*)(bp + kt * 512), acc, 0, 0, 0);
      const int col = ct * 16 + r;
      const float bi = b1[col];
      #pragma unroll
      for (int reg = 0; reg < 4; reg++){
        const float v = acc[reg] + bi;
        const float ge = 0.5f * v * (1.f + erff(v * 0.70710678118f));
        afr[rt][(col >> 3) * 128 + (cg * 4 + reg) * 8 + (col & 7)] = f2bf(ge);
      }
    }
  }
  __syncthreads();
  // ---- phase D: MLP2 + residual (sb) -> out
  {
    const unsigned short* w2 = wpack + 131072;
    f32x4 acc0 = {0.f,0.f,0.f,0.f}, acc1 = {0.f,0.f,0.f,0.f};
    for (int kt = 0; kt < 16; kt++){
      const short8 a3 = *(const short8*)(&afr[rt][(kt * 4 + cg) * 128 + r * 8]);
      const unsigned short* bp0 = w2 + ((size_t)((cgp * 2 + 0) * 16 + kt) * 64 + lane) * 8;
      const unsigned short* bp1 = w2 + ((size_t)((cgp * 2 + 1) * 16 + kt) * 64 + lane) * 8;
      acc0 = __builtin_amdgcn_mfma_f32_16x16x32_bf16(a3, *(const short8*)(bp0), acc0, 0, 0, 0);
      acc1 = __builtin_amdgcn_mfma_f32_16x16x32_bf16(a3, *(const short8*)(bp1), acc1, 0, 0, 0);
    }
    #pragma unroll
    for (int c = 0; c < 2; c++){
      const f32x4 acc = c ? acc1 : acc0;
      const int col = (cgp * 2 + c) * 16 + r;
      const float bi = b2m[col];
      #pragma unroll
      for (int reg = 0; reg < 4; reg++){
        const int tl = rt * 16 + cg * 4 + reg;
        out[(size_t)(tok0 + tl) * 128 + col] = acc[reg] + bi + sb[tl * 128 + col];
      }
    }
  }
}

extern "C" void kernel_launch(void* const* d_in, const int* in_sizes, int n_in,
                              void* d_out, int out_size, void* d_ws, size_t ws_size,
                              hipStream_t stream)
{
  const float* x      = (const float*)d_in[0];
  const float* ln1_g  = (const float*)d_in[1];
  const float* ln1_b  = (const float*)d_in[2];
  const float* qkv_w  = (const float*)d_in[3];
  const float* qkv_b  = (const float*)d_in[4];
  const float* proj_w = (const float*)d_in[5];
  const float* proj_b = (const float*)d_in[6];
  const float* ln2_g  = (const float*)d_in[7];
  const float* ln2_b  = (const float*)d_in[8];
  const float* mlp_w1 = (const float*)d_in[9];
  const float* mlp_b1 = (const float*)d_in[10];
  const float* mlp_w2 = (const float*)d_in[11];
  const float* mlp_b2 = (const float*)d_in[12];

  char* ws = (char*)d_ws;
  unsigned short* wpack   = (unsigned short*)(ws);
  float*          bqs     = (float*)(ws + 393216);
  unsigned short* qkv     = (unsigned short*)(ws + 524288);
  unsigned short* part_ob = (unsigned short*)(ws + 13107200);
  float*          part_l  = (float*)(ws + 29884416);
  float* out = (float*)d_out;

  hipLaunchKernelGGL(k_pack, dim3(96), dim3(256), 0, stream,
                     qkv_w, qkv_b, proj_w, mlp_w1, mlp_w2, wpack, bqs);
  hipLaunchKernelGGL(k_qkv, dim3(256), dim3(512), 0, stream,
                     x, ln1_g, ln1_b, wpack, bqs, qkv);
  hipLaunchKernelGGL(k_attn, dim3(32, 4, 16), dim3(256), 0, stream,
                     qkv, part_ob, part_l);
  hipLaunchKernelGGL(k_fused, dim3(512), dim3(512), 0, stream,
                     part_ob, part_l, x, wpack, proj_b, ln2_g, ln2_b,
                     mlp_b1, mlp_b2, out);
}

// Round 9
// 82.783 us; speedup vs baseline: 4.0741x; 1.0815x over previous
//
#include <hip/hip_runtime.h>
#include <hip/hip_bf16.h>
#include <math.h>

#define NSEQ   4096
#define CDIM   128
#define HD     32

typedef __attribute__((ext_vector_type(8))) short short8;
typedef __attribute__((ext_vector_type(4))) short short4v;
typedef __attribute__((ext_vector_type(4))) float f32x4;

#define QSCL (0.17677669529663687f * 1.4426950408889634f)  // 1/sqrt(32)*log2(e)

__device__ inline unsigned short f2bf(float f){
  union { float f; unsigned u; } v; v.f = f;
  return (unsigned short)((v.u + 0x7fffu + ((v.u >> 16) & 1u)) >> 16);
}
__device__ inline float bf2f(unsigned short u){
  union { unsigned u; float f; } v; v.u = ((unsigned)u) << 16;
  return v.f;
}
__device__ inline void gload_lds16(const unsigned short* g, unsigned short* l){
  __builtin_amdgcn_global_load_lds(
      (const __attribute__((address_space(1))) void*)g,
      (__attribute__((address_space(3))) void*)l, 16, 0, 0);
}

// ---- ws layout (bytes) -----------------------------------------------------
// 0        : wpack u16 [196608] (wq@0, wp@49152, w1@65536, w2@131072)
// 393216   : bqs f32 [384]
// 524288   : qkv u16 48 planes x 131072 (Q[0..15] rowmajor, Kfrag[16..31], Vfrag[32..47])
// 13107200 : part_ob bf16 [2][16][4096][32] (8.4MB)
// 29884416 : part_l f32 [2][16][4096] (0.5MB)

// ---------------- K0: pack weights to MFMA B-fragment layout ----------------
__global__ __launch_bounds__(256) void k_pack(
    const float* __restrict__ qkv_w, const float* __restrict__ qkv_b,
    const float* __restrict__ proj_w, const float* __restrict__ mlp_w1,
    const float* __restrict__ mlp_w2, unsigned short* __restrict__ wpack,
    float* __restrict__ bqs)
{
  const int gt = blockIdx.x * 256 + threadIdx.x;
  const int tile = gt >> 6, lane = gt & 63;
  const float* src; int N, KT, toff, dstoff; float scale = 1.f;
  if (tile < 96)       { src = qkv_w;  N = 384; KT = 4;  toff = tile;       dstoff = 0; }
  else if (tile < 128) { src = proj_w; N = 128; KT = 4;  toff = tile - 96;  dstoff = 49152; }
  else if (tile < 256) { src = mlp_w1; N = 512; KT = 4;  toff = tile - 128; dstoff = 65536; }
  else                 { src = mlp_w2; N = 128; KT = 16; toff = tile - 256; dstoff = 131072; }
  const int ct = toff / KT, kt = toff % KT;
  if (tile < 96 && ct < 8) scale = QSCL;   // Q columns
  const int row0 = kt * 32 + (lane >> 4) * 8, col = ct * 16 + (lane & 15);
  short8 v;
  #pragma unroll
  for (int i = 0; i < 8; i++)
    v[i] = (short)f2bf(src[(size_t)(row0 + i) * N + col] * scale);
  *(short8*)(wpack + dstoff + ((size_t)(ct * KT + kt) * 64 + lane) * 8) = v;
  if (gt < 384) bqs[gt] = qkv_b[gt] * (gt < 128 ? QSCL : 1.f);
}

// ---------------- K1: LN1 + QKV MFMA GEMM -----------------------------------
__global__ __launch_bounds__(512) void k_qkv(
    const float* __restrict__ x, const float* __restrict__ g,
    const float* __restrict__ b, const unsigned short* __restrict__ wpack,
    const float* __restrict__ bqs, unsigned short* __restrict__ qkv)
{
  __shared__ unsigned short xn[64 * 128];
  const int tid = threadIdx.x;
  const int tok0 = blockIdx.x * 64;
  {
    const int grp = tid >> 5, l = tid & 31;
    #pragma unroll
    for (int it = 0; it < 4; it++){
      const int t = it * 16 + grp;
      const float4 xv = *(const float4*)(x + (size_t)(tok0 + t) * 128 + l * 4);
      float s  = xv.x + xv.y + xv.z + xv.w;
      float s2 = xv.x*xv.x + xv.y*xv.y + xv.z*xv.z + xv.w*xv.w;
      #pragma unroll
      for (int m = 1; m <= 16; m <<= 1){ s += __shfl_xor(s, m); s2 += __shfl_xor(s2, m); }
      const float mu = s * (1.f/128.f);
      const float rs = rsqrtf(s2 * (1.f/128.f) - mu*mu + 1e-5f);
      const int e = l * 4;
      const float4 gv = *(const float4*)(g + e), bv = *(const float4*)(b + e);
      short4v pk;
      pk[0] = (short)f2bf((xv.x - mu)*rs*gv.x + bv.x);
      pk[1] = (short)f2bf((xv.y - mu)*rs*gv.y + bv.y);
      pk[2] = (short)f2bf((xv.z - mu)*rs*gv.z + bv.z);
      pk[3] = (short)f2bf((xv.w - mu)*rs*gv.w + bv.w);
      const int bl = l >> 1;
      const int slot = bl * 64 + (t & 48) + ((t & 15) ^ bl);
      *(short4v*)(xn + slot * 8 + (l & 1) * 4) = pk;
    }
  }
  __syncthreads();
  const int wv = tid >> 6, lane = tid & 63, r = lane & 15, cg = lane >> 4;
  const int rt = wv & 3, ct0 = (wv >> 2) * 12;
  short8 af[4];
  #pragma unroll
  for (int kt = 0; kt < 4; kt++){
    const int bl = kt * 4 + cg;
    const int slot = bl * 64 + rt * 16 + (r ^ bl);
    af[kt] = *(const short8*)(xn + slot * 8);
  }
  const int bidx = tok0 >> 12, nloc = (tok0 & (NSEQ - 1)) + rt * 16 + cg * 4;
  for (int ct = ct0; ct < ct0 + 12; ct++){
    f32x4 acc = {0.f, 0.f, 0.f, 0.f};
    const unsigned short* bp = wpack + ((size_t)(ct * 4) * 64 + lane) * 8;
    #pragma unroll
    for (int kt = 0; kt < 4; kt++)
      acc = __builtin_amdgcn_mfma_f32_16x16x32_bf16(af[kt], *(const short8*)(bp + kt * 512), acc, 0, 0, 0);
    const int col = ct * 16 + r;
    const float bi = bqs[col];
    if (ct < 8){                                   // Q: row-major [n][32]
      const int cc = col & 127, h = cc >> 5, d = cc & 31;
      unsigned short* plane = qkv + ((size_t)bidx * 4 + h) * (NSEQ * HD);
      #pragma unroll
      for (int reg = 0; reg < 4; reg++)
        plane[(size_t)(nloc + reg) * HD + d] = f2bf(acc[reg] + bi);
    } else if (ct < 16){                           // K: A-fragment layout per 16-row tile
      const int cc = col & 127, h = cc >> 5, d = cc & 31;
      unsigned short* plane = qkv + ((size_t)16 + bidx * 4 + h) * (NSEQ * HD);
      const int t16 = ((tok0 & (NSEQ - 1)) >> 4) + rt;
      #pragma unroll
      for (int reg = 0; reg < 4; reg++)
        plane[(size_t)t16 * 512 + (d >> 3) * 128 + (cg * 4 + reg) * 8 + (d & 7)]
            = f2bf(acc[reg] + bi);
    } else {                                       // V: PV-fragment layout
      const int vct = ct - 16, h = vct >> 1, half = vct & 1;
      unsigned short* plane = qkv + ((size_t)32 + bidx * 4 + h) * (NSEQ * HD);
      const size_t ntile = (size_t)((tok0 & (NSEQ - 1)) >> 5) + (rt >> 1);
      const size_t vo = (ntile * 2 + half) * 512 + lane * 8 + (rt & 1) * 4;
      short4v pk;
      #pragma unroll
      for (int reg = 0; reg < 4; reg++) pk[reg] = (short)f2bf(acc[reg] + bi);
      *(short4v*)(plane + vo) = pk;
    }
  }
}

// ---------------- K2: flash attention, KVBLK=64, 4-deep pipelined ring ------
// grid (32, 2, 16); block 256 (4 waves). Block: 128 q rows, chunk 2048 keys.
// Per iter: 8KB staged (K 4KB + V 4KB, 64 keys); each wave issues exactly 2
// global_load_lds -> counted wait is vmcnt(4) (3 iters x 2 loads in flight).
// 20 MFMA + 32 exp per barrier (2x r8) to amortize sync latency.
__global__ __launch_bounds__(256, 4) void k_attn(
    const unsigned short* __restrict__ qkv, unsigned short* __restrict__ part_ob,
    float* __restrict__ part_l)
{
  __shared__ unsigned short sbuf[16384];   // 32KB: 4 slots x (K 4KB + V 4KB)
  const int tid = threadIdx.x;
  const int lane = tid & 63, wv = tid >> 6;
  const int chunk = blockIdx.y, bh = blockIdx.z;
  const int qbase = blockIdx.x * 128 + wv * 32;
  const int kv0 = chunk * 2048;
  const unsigned short* Q  = qkv + (size_t)bh * (NSEQ * HD);
  const unsigned short* Kc = qkv + (size_t)(16 + bh) * (NSEQ * HD) + (size_t)kv0 * HD;
  const unsigned short* Vc = qkv + (size_t)(32 + bh) * (NSEQ * HD) + (size_t)kv0 * HD;
  const int r = lane & 15, cg = lane >> 4;
  const short8 qf0 = *(const short8*)(Q + (size_t)(qbase + r) * HD + cg * 8);
  const short8 qf1 = *(const short8*)(Q + (size_t)(qbase + 16 + r) * HD + cg * 8);
  // staging: wave w loads K-quarter w (1KB) and V-quarter w (1KB) each iter
  const unsigned short* gK = Kc + wv * 512 + lane * 8;
  const unsigned short* gV = Vc + wv * 512 + lane * 8;
  const int dK = wv * 512, dV = 2048 + wv * 512;     // u16 offsets within slot
  union { unsigned u[4]; short8 s; } onesu;
  onesu.u[0] = 0x3F803F80u; onesu.u[1] = 0x3F803F80u;
  onesu.u[2] = 0x3F803F80u; onesu.u[3] = 0x3F803F80u;
  const short8 vones = onesu.s;
  f32x4 o00 = {0.f,0.f,0.f,0.f}, o01 = {0.f,0.f,0.f,0.f};
  f32x4 o10 = {0.f,0.f,0.f,0.f}, o11 = {0.f,0.f,0.f,0.f};
  f32x4 lacc0 = {0.f,0.f,0.f,0.f}, lacc1 = {0.f,0.f,0.f,0.f};
  const f32x4 zero = {0.f,0.f,0.f,0.f};
  // prologue: 3-deep prefetch (slots 0,1,2); issue order K,V per slot
  gload_lds16(gK,        sbuf + 0 * 4096 + dK);
  gload_lds16(gV,        sbuf + 0 * 4096 + dV);
  gload_lds16(gK + 2048, sbuf + 1 * 4096 + dK);
  gload_lds16(gV + 2048, sbuf + 1 * 4096 + dV);
  gload_lds16(gK + 4096, sbuf + 2 * 4096 + dK);
  gload_lds16(gV + 4096, sbuf + 2 * 4096 + dV);
  for (int t = 0; t < 32; t++){
    // own K/V of iter t landed (vmcnt(4): exactly 6 outstanding, oldest 2
    // are iter t's) AND own prior-iter LDS reads done, BEFORE barrier.
    asm volatile("s_waitcnt vmcnt(4) lgkmcnt(0)" ::: "memory");
    __builtin_amdgcn_sched_barrier(0);
    __builtin_amdgcn_s_barrier();
    __builtin_amdgcn_sched_barrier(0);
    const int tn = (t + 3 > 31) ? 31 : t + 3;   // clamped dummy keeps vmcnt uniform
    gload_lds16(gK + (size_t)tn * 2048, sbuf + ((t + 3) & 3) * 4096 + dK);
    gload_lds16(gV + (size_t)tn * 2048, sbuf + ((t + 3) & 3) * 4096 + dV);
    const unsigned short* skb = sbuf + (t & 3) * 4096;
    const unsigned short* svb = skb + 2048;
    #pragma unroll
    for (int ktp = 0; ktp < 2; ktp++){
      const short8 kaa = *(const short8*)(skb + (ktp * 2 + 0) * 512 + lane * 8);
      const short8 kab = *(const short8*)(skb + (ktp * 2 + 1) * 512 + lane * 8);
      const short8 va0 = *(const short8*)(svb + (ktp * 2 + 0) * 512 + lane * 8);
      const short8 va1 = *(const short8*)(svb + (ktp * 2 + 1) * 512 + lane * 8);
      const f32x4 s00 = __builtin_amdgcn_mfma_f32_16x16x32_bf16(kaa, qf0, zero, 0, 0, 0);
      const f32x4 s01 = __builtin_amdgcn_mfma_f32_16x16x32_bf16(kab, qf0, zero, 0, 0, 0);
      const f32x4 s10 = __builtin_amdgcn_mfma_f32_16x16x32_bf16(kaa, qf1, zero, 0, 0, 0);
      const f32x4 s11 = __builtin_amdgcn_mfma_f32_16x16x32_bf16(kab, qf1, zero, 0, 0, 0);
      float p00[4], p01[4], p10[4], p11[4];
      #pragma unroll
      for (int i = 0; i < 4; i++){
        p00[i] = __builtin_amdgcn_exp2f(s00[i]);
        p01[i] = __builtin_amdgcn_exp2f(s01[i]);
        p10[i] = __builtin_amdgcn_exp2f(s10[i]);
        p11[i] = __builtin_amdgcn_exp2f(s11[i]);
      }
      unsigned c0, c1, c2, c3, c4, c5, c6, c7;
      asm("v_cvt_pk_bf16_f32 %0, %1, %2" : "=v"(c0) : "v"(p00[0]), "v"(p00[1]));
      asm("v_cvt_pk_bf16_f32 %0, %1, %2" : "=v"(c1) : "v"(p00[2]), "v"(p00[3]));
      asm("v_cvt_pk_bf16_f32 %0, %1, %2" : "=v"(c2) : "v"(p01[0]), "v"(p01[1]));
      asm("v_cvt_pk_bf16_f32 %0, %1, %2" : "=v"(c3) : "v"(p01[2]), "v"(p01[3]));
      asm("v_cvt_pk_bf16_f32 %0, %1, %2" : "=v"(c4) : "v"(p10[0]), "v"(p10[1]));
      asm("v_cvt_pk_bf16_f32 %0, %1, %2" : "=v"(c5) : "v"(p10[2]), "v"(p10[3]));
      asm("v_cvt_pk_bf16_f32 %0, %1, %2" : "=v"(c6) : "v"(p11[0]), "v"(p11[1]));
      asm("v_cvt_pk_bf16_f32 %0, %1, %2" : "=v"(c7) : "v"(p11[2]), "v"(p11[3]));
      union { unsigned u[4]; short8 s; } pa, pb;
      pa.u[0] = c0; pa.u[1] = c1; pa.u[2] = c2; pa.u[3] = c3;
      pb.u[0] = c4; pb.u[1] = c5; pb.u[2] = c6; pb.u[3] = c7;
      o00 = __builtin_amdgcn_mfma_f32_16x16x32_bf16(va0, pa.s, o00, 0, 0, 0);
      o01 = __builtin_amdgcn_mfma_f32_16x16x32_bf16(va1, pa.s, o01, 0, 0, 0);
      o10 = __builtin_amdgcn_mfma_f32_16x16x32_bf16(va0, pb.s, o10, 0, 0, 0);
      o11 = __builtin_amdgcn_mfma_f32_16x16x32_bf16(va1, pb.s, o11, 0, 0, 0);
      lacc0 = __builtin_amdgcn_mfma_f32_16x16x32_bf16(vones, pa.s, lacc0, 0, 0, 0);
      lacc1 = __builtin_amdgcn_mfma_f32_16x16x32_bf16(vones, pb.s, lacc1, 0, 0, 0);
    }
  }
  // drain trailing dummy LDS-DMA writes before workgroup exit
  asm volatile("s_waitcnt vmcnt(0)" ::: "memory");
  const float ls0 = lacc0[0], ls1 = lacc1[0];   // all regs/lane-groups equal
  unsigned short* po = part_ob + (((size_t)(chunk * 16 + bh) * NSEQ) + qbase + r) * HD;
  short4v w0, w1, w2, w3;
  #pragma unroll
  for (int j = 0; j < 4; j++){
    w0[j] = (short)f2bf(o00[j]); w1[j] = (short)f2bf(o01[j]);
    w2[j] = (short)f2bf(o10[j]); w3[j] = (short)f2bf(o11[j]);
  }
  *(short4v*)(po + cg * 4)              = w0;
  *(short4v*)(po + 16 + cg * 4)         = w1;
  *(short4v*)(po + 16 * HD + cg * 4)    = w2;
  *(short4v*)(po + 16 * HD + 16 + cg * 4) = w3;
  if (lane < 16){
    part_l[(size_t)(chunk * 16 + bh) * NSEQ + qbase + r] = ls0;
    part_l[(size_t)(chunk * 16 + bh) * NSEQ + qbase + 16 + r] = ls1;
  }
}

// ---------------- K3: fused reduce + proj + LN2 + MLP1 + GELU + MLP2 --------
// block: 32 tokens, 512 threads (8 waves: rt = wv&1, cgp = wv>>1).
// LDS 56KB -> 2 blocks/CU. Residual and activations never touch global.
__global__ __launch_bounds__(512, 2) void k_fused(
    const unsigned short* __restrict__ part_ob, const float* __restrict__ part_l,
    const float* __restrict__ x, const unsigned short* __restrict__ wpack,
    const float* __restrict__ pb, const float* __restrict__ g2,
    const float* __restrict__ b2, const float* __restrict__ b1,
    const float* __restrict__ b2m, float* __restrict__ out)
{
  __shared__ float sb[32 * 128];             // 16KB residual (x + attn@proj)
  __shared__ unsigned short hfr[2][2048];    //  8KB LN2 output, A-frag layout
  __shared__ unsigned short afr[2][8192];    // 32KB GELU acts, A-frag layout
  const int tid = threadIdx.x, tok0 = blockIdx.x * 32;
  const int wv = tid >> 6, lane = tid & 63, r = lane & 15, cg = lane >> 4;
  const int rt = wv & 1, cgp = wv >> 1;
  const int bidx = tok0 >> 12, qn0 = (tok0 & (NSEQ - 1)) + rt * 16 + r;
  // ---- phase A: fused softmax-reduce -> proj A-frag; proj MFMA; residual
  short8 af[4];
  #pragma unroll
  for (int kt = 0; kt < 4; kt++){
    const int bh = bidx * 4 + kt;
    float s8[8] = {0.f,0.f,0.f,0.f,0.f,0.f,0.f,0.f};
    float lsum = 0.f;
    #pragma unroll
    for (int c = 0; c < 2; c++){
      const short8 v = *(const short8*)(part_ob +
          (((size_t)(c * 16 + bh) * NSEQ) + qn0) * HD + cg * 8);
      #pragma unroll
      for (int i = 0; i < 8; i++) s8[i] += bf2f((unsigned short)v[i]);
      lsum += part_l[(size_t)(c * 16 + bh) * NSEQ + qn0];
    }
    const float inv = 1.f / lsum;
    #pragma unroll
    for (int i = 0; i < 8; i++) af[kt][i] = (short)f2bf(s8[i] * inv);
  }
  {
    const unsigned short* wp = wpack + 49152;
    for (int ct = cgp * 2; ct < cgp * 2 + 2; ct++){
      f32x4 acc = {0.f, 0.f, 0.f, 0.f};
      const unsigned short* bp = wp + ((size_t)(ct * 4) * 64 + lane) * 8;
      #pragma unroll
      for (int kt = 0; kt < 4; kt++)
        acc = __builtin_amdgcn_mfma_f32_16x16x32_bf16(af[kt], *(const short8*)(bp + kt * 512), acc, 0, 0, 0);
      const int col = ct * 16 + r;
      const float bi = pb[col];
      #pragma unroll
      for (int reg = 0; reg < 4; reg++){
        const int tl = rt * 16 + cg * 4 + reg;
        sb[tl * 128 + col] = acc[reg] + bi + x[(size_t)(tok0 + tl) * 128 + col];
      }
    }
  }
  __syncthreads();
  // ---- phase B: LN2 -> hfr (A-fragment layout in LDS)
  {
    const int grp = tid >> 5, l = tid & 31;
    #pragma unroll
    for (int it = 0; it < 2; it++){
      const int t = it * 16 + grp;
      const float4 xv = *(const float4*)(sb + t * 128 + l * 4);
      float s  = xv.x + xv.y + xv.z + xv.w;
      float s2 = xv.x*xv.x + xv.y*xv.y + xv.z*xv.z + xv.w*xv.w;
      #pragma unroll
      for (int m = 1; m <= 16; m <<= 1){ s += __shfl_xor(s, m); s2 += __shfl_xor(s2, m); }
      const float mu = s * (1.f/128.f);
      const float rs = rsqrtf(s2 * (1.f/128.f) - mu*mu + 1e-5f);
      const int e = l * 4;
      const float4 gv = *(const float4*)(g2 + e), bv = *(const float4*)(b2 + e);
      short4v pk;
      pk[0] = (short)f2bf((xv.x - mu)*rs*gv.x + bv.x);
      pk[1] = (short)f2bf((xv.y - mu)*rs*gv.y + bv.y);
      pk[2] = (short)f2bf((xv.z - mu)*rs*gv.z + bv.z);
      pk[3] = (short)f2bf((xv.w - mu)*rs*gv.w + bv.w);
      // element (t, e+j) -> frag pos (e>>3)*128 + (t&15)*8 + (e&7)+j
      *(short4v*)(&hfr[t >> 4][(e >> 3) * 128 + (t & 15) * 8 + (e & 7)]) = pk;
    }
  }
  __syncthreads();
  // ---- phase C: MLP1 + GELU -> afr (A-fragment layout)
  {
    short8 hf[4];
    #pragma unroll
    for (int kt = 0; kt < 4; kt++)
      hf[kt] = *(const short8*)(&hfr[rt][(kt * 4 + cg) * 128 + r * 8]);
    const unsigned short* w1 = wpack + 65536;
    for (int ct = cgp * 8; ct < cgp * 8 + 8; ct++){
      f32x4 acc = {0.f, 0.f, 0.f, 0.f};
      const unsigned short* bp = w1 + ((size_t)(ct * 4) * 64 + lane) * 8;
      #pragma unroll
      for (int kt = 0; kt < 4; kt++)
        acc = __builtin_amdgcn_mfma_f32_16x16x32_bf16(hf[kt], *(const short8*)(bp + kt * 512), acc, 0, 0, 0);
      const int col = ct * 16 + r;
      const float bi = b1[col];
      #pragma unroll
      for (int reg = 0; reg < 4; reg++){
        const float v = acc[reg] + bi;
        const float ge = 0.5f * v * (1.f + erff(v * 0.70710678118f));
        afr[rt][(col >> 3) * 128 + (cg * 4 + reg) * 8 + (col & 7)] = f2bf(ge);
      }
    }
  }
  __syncthreads();
  // ---- phase D: MLP2 + residual (sb) -> out
  {
    const unsigned short* w2 = wpack + 131072;
    f32x4 acc0 = {0.f,0.f,0.f,0.f}, acc1 = {0.f,0.f,0.f,0.f};
    for (int kt = 0; kt < 16; kt++){
      const short8 a3 = *(const short8*)(&afr[rt][(kt * 4 + cg) * 128 + r * 8]);
      const unsigned short* bp0 = w2 + ((size_t)((cgp * 2 + 0) * 16 + kt) * 64 + lane) * 8;
      const unsigned short* bp1 = w2 + ((size_t)((cgp * 2 + 1) * 16 + kt) * 64 + lane) * 8;
      acc0 = __builtin_amdgcn_mfma_f32_16x16x32_bf16(a3, *(const short8*)(bp0), acc0, 0, 0, 0);
      acc1 = __builtin_amdgcn_mfma_f32_16x16x32_bf16(a3, *(const short8*)(bp1), acc1, 0, 0, 0);
    }
    #pragma unroll
    for (int c = 0; c < 2; c++){
      const f32x4 acc = c ? acc1 : acc0;
      const int col = (cgp * 2 + c) * 16 + r;
      const float bi = b2m[col];
      #pragma unroll
      for (int reg = 0; reg < 4; reg++){
        const int tl = rt * 16 + cg * 4 + reg;
        out[(size_t)(tok0 + tl) * 128 + col] = acc[reg] + bi + sb[tl * 128 + col];
      }
    }
  }
}

extern "C" void kernel_launch(void* const* d_in, const int* in_sizes, int n_in,
                              void* d_out, int out_size, void* d_ws, size_t ws_size,
                              hipStream_t stream)
{
  const float* x      = (const float*)d_in[0];
  const float* ln1_g  = (const float*)d_in[1];
  const float* ln1_b  = (const float*)d_in[2];
  const float* qkv_w  = (const float*)d_in[3];
  const float* qkv_b  = (const float*)d_in[4];
  const float* proj_w = (const float*)d_in[5];
  const float* proj_b = (const float*)d_in[6];
  const float* ln2_g  = (const float*)d_in[7];
  const float* ln2_b  = (const float*)d_in[8];
  const float* mlp_w1 = (const float*)d_in[9];
  const float* mlp_b1 = (const float*)d_in[10];
  const float* mlp_w2 = (const float*)d_in[11];
  const float* mlp_b2 = (const float*)d_in[12];

  char* ws = (char*)d_ws;
  unsigned short* wpack   = (unsigned short*)(ws);
  float*          bqs     = (float*)(ws + 393216);
  unsigned short* qkv     = (unsigned short*)(ws + 524288);
  unsigned short* part_ob = (unsigned short*)(ws + 13107200);
  float*          part_l  = (float*)(ws + 29884416);
  float* out = (float*)d_out;

  hipLaunchKernelGGL(k_pack, dim3(96), dim3(256), 0, stream,
                     qkv_w, qkv_b, proj_w, mlp_w1, mlp_w2, wpack, bqs);
  hipLaunchKernelGGL(k_qkv, dim3(256), dim3(512), 0, stream,
                     x, ln1_g, ln1_b, wpack, bqs, qkv);
  hipLaunchKernelGGL(k_attn, dim3(32, 2, 16), dim3(256), 0, stream,
                     qkv, part_ob, part_l);
  hipLaunchKernelGGL(k_fused, dim3(512), dim3(512), 0, stream,
                     part_ob, part_l, x, wpack, proj_b, ln2_g, ln2_b,
                     mlp_b1, mlp_b2, out);
}

// Round 10
// 81.410 us; speedup vs baseline: 4.1428x; 1.0169x over previous
//
#include <hip/hip_runtime.h>
#include <hip/hip_bf16.h>
#include <math.h>

#define NSEQ   4096
#define CDIM   128
#define HD     32

typedef __attribute__((ext_vector_type(8))) short short8;
typedef __attribute__((ext_vector_type(4))) short short4v;
typedef __attribute__((ext_vector_type(4))) float f32x4;

#define QSCL (0.17677669529663687f * 1.4426950408889634f)  // 1/sqrt(32)*log2(e)

__device__ inline unsigned short f2bf(float f){
  union { float f; unsigned u; } v; v.f = f;
  return (unsigned short)((v.u + 0x7fffu + ((v.u >> 16) & 1u)) >> 16);
}
__device__ inline float bf2f(unsigned short u){
  union { unsigned u; float f; } v; v.u = ((unsigned)u) << 16;
  return v.f;
}
__device__ inline void gload_lds16(const unsigned short* g, unsigned short* l){
  __builtin_amdgcn_global_load_lds(
      (const __attribute__((address_space(1))) void*)g,
      (__attribute__((address_space(3))) void*)l, 16, 0, 0);
}

// ---- ws layout (bytes) -----------------------------------------------------
// 0        : wpack u16 [196608] (wq@0, wp@49152, w1@65536, w2@131072)
// 393216   : bqs f32 [384]
// 524288   : qkv u16 48 planes x 131072 (Q[0..15] rowmajor, Kfrag[16..31], Vfrag[32..47])
// 13107200 : part_ob bf16 [2][16][4096][32] (8.4MB)
// 29884416 : part_l f32 [2][16][4096] (0.5MB)

// ---------------- K0: pack weights to MFMA B-fragment layout ----------------
__global__ __launch_bounds__(256) void k_pack(
    const float* __restrict__ qkv_w, const float* __restrict__ qkv_b,
    const float* __restrict__ proj_w, const float* __restrict__ mlp_w1,
    const float* __restrict__ mlp_w2, unsigned short* __restrict__ wpack,
    float* __restrict__ bqs)
{
  const int gt = blockIdx.x * 256 + threadIdx.x;
  const int tile = gt >> 6, lane = gt & 63;
  const float* src; int N, KT, toff, dstoff; float scale = 1.f;
  if (tile < 96)       { src = qkv_w;  N = 384; KT = 4;  toff = tile;       dstoff = 0; }
  else if (tile < 128) { src = proj_w; N = 128; KT = 4;  toff = tile - 96;  dstoff = 49152; }
  else if (tile < 256) { src = mlp_w1; N = 512; KT = 4;  toff = tile - 128; dstoff = 65536; }
  else                 { src = mlp_w2; N = 128; KT = 16; toff = tile - 256; dstoff = 131072; }
  const int ct = toff / KT, kt = toff % KT;
  if (tile < 96 && ct < 8) scale = QSCL;   // Q columns
  const int row0 = kt * 32 + (lane >> 4) * 8, col = ct * 16 + (lane & 15);
  short8 v;
  #pragma unroll
  for (int i = 0; i < 8; i++)
    v[i] = (short)f2bf(src[(size_t)(row0 + i) * N + col] * scale);
  *(short8*)(wpack + dstoff + ((size_t)(ct * KT + kt) * 64 + lane) * 8) = v;
  if (gt < 384) bqs[gt] = qkv_b[gt] * (gt < 128 ? QSCL : 1.f);
}

// ---------------- K1: LN1 + QKV MFMA GEMM (32 tokens/block, 2 blocks/CU) ----
__global__ __launch_bounds__(512) void k_qkv(
    const float* __restrict__ x, const float* __restrict__ g,
    const float* __restrict__ b, const unsigned short* __restrict__ wpack,
    const float* __restrict__ bqs, unsigned short* __restrict__ qkv)
{
  __shared__ unsigned short xn[32 * 128];
  const int tid = threadIdx.x;
  const int tok0 = blockIdx.x * 32;
  {
    const int grp = tid >> 5, l = tid & 31;
    #pragma unroll
    for (int it = 0; it < 2; it++){
      const int t = it * 16 + grp;
      const float4 xv = *(const float4*)(x + (size_t)(tok0 + t) * 128 + l * 4);
      float s  = xv.x + xv.y + xv.z + xv.w;
      float s2 = xv.x*xv.x + xv.y*xv.y + xv.z*xv.z + xv.w*xv.w;
      #pragma unroll
      for (int m = 1; m <= 16; m <<= 1){ s += __shfl_xor(s, m); s2 += __shfl_xor(s2, m); }
      const float mu = s * (1.f/128.f);
      const float rs = rsqrtf(s2 * (1.f/128.f) - mu*mu + 1e-5f);
      const int e = l * 4;
      const float4 gv = *(const float4*)(g + e), bv = *(const float4*)(b + e);
      short4v pk;
      pk[0] = (short)f2bf((xv.x - mu)*rs*gv.x + bv.x);
      pk[1] = (short)f2bf((xv.y - mu)*rs*gv.y + bv.y);
      pk[2] = (short)f2bf((xv.z - mu)*rs*gv.z + bv.z);
      pk[3] = (short)f2bf((xv.w - mu)*rs*gv.w + bv.w);
      const int bl = l >> 1;
      const int slot = bl * 32 + (t & 16) + ((t & 15) ^ bl);
      *(short4v*)(xn + slot * 8 + (l & 1) * 4) = pk;
    }
  }
  __syncthreads();
  const int wv = tid >> 6, lane = tid & 63, r = lane & 15, cg = lane >> 4;
  const int rt = wv & 1, ct0 = (wv >> 1) * 6;
  short8 af[4];
  #pragma unroll
  for (int kt = 0; kt < 4; kt++){
    const int bl = kt * 4 + cg;
    const int slot = bl * 32 + rt * 16 + (r ^ bl);
    af[kt] = *(const short8*)(xn + slot * 8);
  }
  const int bidx = tok0 >> 12, nloc = (tok0 & (NSEQ - 1)) + rt * 16 + cg * 4;
  for (int ct = ct0; ct < ct0 + 6; ct++){
    f32x4 acc = {0.f, 0.f, 0.f, 0.f};
    const unsigned short* bp = wpack + ((size_t)(ct * 4) * 64 + lane) * 8;
    #pragma unroll
    for (int kt = 0; kt < 4; kt++)
      acc = __builtin_amdgcn_mfma_f32_16x16x32_bf16(af[kt], *(const short8*)(bp + kt * 512), acc, 0, 0, 0);
    const int col = ct * 16 + r;
    const float bi = bqs[col];
    if (ct < 8){                                   // Q: row-major [n][32]
      const int cc = col & 127, h = cc >> 5, d = cc & 31;
      unsigned short* plane = qkv + ((size_t)bidx * 4 + h) * (NSEQ * HD);
      #pragma unroll
      for (int reg = 0; reg < 4; reg++)
        plane[(size_t)(nloc + reg) * HD + d] = f2bf(acc[reg] + bi);
    } else if (ct < 16){                           // K: A-fragment layout per 16-row tile
      const int cc = col & 127, h = cc >> 5, d = cc & 31;
      unsigned short* plane = qkv + ((size_t)16 + bidx * 4 + h) * (NSEQ * HD);
      const int t16 = ((tok0 & (NSEQ - 1)) >> 4) + rt;
      #pragma unroll
      for (int reg = 0; reg < 4; reg++)
        plane[(size_t)t16 * 512 + (d >> 3) * 128 + (cg * 4 + reg) * 8 + (d & 7)]
            = f2bf(acc[reg] + bi);
    } else {                                       // V: PV-fragment layout
      const int vct = ct - 16, h = vct >> 1, half = vct & 1;
      unsigned short* plane = qkv + ((size_t)32 + bidx * 4 + h) * (NSEQ * HD);
      const size_t ntile = (size_t)((tok0 & (NSEQ - 1)) >> 5);
      const size_t vo = (ntile * 2 + half) * 512 + lane * 8 + rt * 4;
      short4v pk;
      #pragma unroll
      for (int reg = 0; reg < 4; reg++) pk[reg] = (short)f2bf(acc[reg] + bi);
      *(short4v*)(plane + vo) = pk;
    }
  }
}

// ---------------- K2: flash attention, KVBLK=64, 4-deep pipelined ring ------
// grid (32, 2, 16); block 256 (4 waves). Block: 128 q rows, chunk 2048 keys.
__global__ __launch_bounds__(256, 4) void k_attn(
    const unsigned short* __restrict__ qkv, unsigned short* __restrict__ part_ob,
    float* __restrict__ part_l)
{
  __shared__ unsigned short sbuf[16384];   // 32KB: 4 slots x (K 4KB + V 4KB)
  const int tid = threadIdx.x;
  const int lane = tid & 63, wv = tid >> 6;
  const int chunk = blockIdx.y, bh = blockIdx.z;
  const int qbase = blockIdx.x * 128 + wv * 32;
  const int kv0 = chunk * 2048;
  const unsigned short* Q  = qkv + (size_t)bh * (NSEQ * HD);
  const unsigned short* Kc = qkv + (size_t)(16 + bh) * (NSEQ * HD) + (size_t)kv0 * HD;
  const unsigned short* Vc = qkv + (size_t)(32 + bh) * (NSEQ * HD) + (size_t)kv0 * HD;
  const int r = lane & 15, cg = lane >> 4;
  const short8 qf0 = *(const short8*)(Q + (size_t)(qbase + r) * HD + cg * 8);
  const short8 qf1 = *(const short8*)(Q + (size_t)(qbase + 16 + r) * HD + cg * 8);
  const unsigned short* gK = Kc + wv * 512 + lane * 8;
  const unsigned short* gV = Vc + wv * 512 + lane * 8;
  const int dK = wv * 512, dV = 2048 + wv * 512;     // u16 offsets within slot
  union { unsigned u[4]; short8 s; } onesu;
  onesu.u[0] = 0x3F803F80u; onesu.u[1] = 0x3F803F80u;
  onesu.u[2] = 0x3F803F80u; onesu.u[3] = 0x3F803F80u;
  const short8 vones = onesu.s;
  f32x4 o00 = {0.f,0.f,0.f,0.f}, o01 = {0.f,0.f,0.f,0.f};
  f32x4 o10 = {0.f,0.f,0.f,0.f}, o11 = {0.f,0.f,0.f,0.f};
  f32x4 lacc0 = {0.f,0.f,0.f,0.f}, lacc1 = {0.f,0.f,0.f,0.f};
  const f32x4 zero = {0.f,0.f,0.f,0.f};
  gload_lds16(gK,        sbuf + 0 * 4096 + dK);
  gload_lds16(gV,        sbuf + 0 * 4096 + dV);
  gload_lds16(gK + 2048, sbuf + 1 * 4096 + dK);
  gload_lds16(gV + 2048, sbuf + 1 * 4096 + dV);
  gload_lds16(gK + 4096, sbuf + 2 * 4096 + dK);
  gload_lds16(gV + 4096, sbuf + 2 * 4096 + dV);
  for (int t = 0; t < 32; t++){
    asm volatile("s_waitcnt vmcnt(4) lgkmcnt(0)" ::: "memory");
    __builtin_amdgcn_sched_barrier(0);
    __builtin_amdgcn_s_barrier();
    __builtin_amdgcn_sched_barrier(0);
    const int tn = (t + 3 > 31) ? 31 : t + 3;   // clamped dummy keeps vmcnt uniform
    gload_lds16(gK + (size_t)tn * 2048, sbuf + ((t + 3) & 3) * 4096 + dK);
    gload_lds16(gV + (size_t)tn * 2048, sbuf + ((t + 3) & 3) * 4096 + dV);
    const unsigned short* skb = sbuf + (t & 3) * 4096;
    const unsigned short* svb = skb + 2048;
    #pragma unroll
    for (int ktp = 0; ktp < 2; ktp++){
      const short8 kaa = *(const short8*)(skb + (ktp * 2 + 0) * 512 + lane * 8);
      const short8 kab = *(const short8*)(skb + (ktp * 2 + 1) * 512 + lane * 8);
      const short8 va0 = *(const short8*)(svb + (ktp * 2 + 0) * 512 + lane * 8);
      const short8 va1 = *(const short8*)(svb + (ktp * 2 + 1) * 512 + lane * 8);
      const f32x4 s00 = __builtin_amdgcn_mfma_f32_16x16x32_bf16(kaa, qf0, zero, 0, 0, 0);
      const f32x4 s01 = __builtin_amdgcn_mfma_f32_16x16x32_bf16(kab, qf0, zero, 0, 0, 0);
      const f32x4 s10 = __builtin_amdgcn_mfma_f32_16x16x32_bf16(kaa, qf1, zero, 0, 0, 0);
      const f32x4 s11 = __builtin_amdgcn_mfma_f32_16x16x32_bf16(kab, qf1, zero, 0, 0, 0);
      float p00[4], p01[4], p10[4], p11[4];
      #pragma unroll
      for (int i = 0; i < 4; i++){
        p00[i] = __builtin_amdgcn_exp2f(s00[i]);
        p01[i] = __builtin_amdgcn_exp2f(s01[i]);
        p10[i] = __builtin_amdgcn_exp2f(s10[i]);
        p11[i] = __builtin_amdgcn_exp2f(s11[i]);
      }
      unsigned c0, c1, c2, c3, c4, c5, c6, c7;
      asm("v_cvt_pk_bf16_f32 %0, %1, %2" : "=v"(c0) : "v"(p00[0]), "v"(p00[1]));
      asm("v_cvt_pk_bf16_f32 %0, %1, %2" : "=v"(c1) : "v"(p00[2]), "v"(p00[3]));
      asm("v_cvt_pk_bf16_f32 %0, %1, %2" : "=v"(c2) : "v"(p01[0]), "v"(p01[1]));
      asm("v_cvt_pk_bf16_f32 %0, %1, %2" : "=v"(c3) : "v"(p01[2]), "v"(p01[3]));
      asm("v_cvt_pk_bf16_f32 %0, %1, %2" : "=v"(c4) : "v"(p10[0]), "v"(p10[1]));
      asm("v_cvt_pk_bf16_f32 %0, %1, %2" : "=v"(c5) : "v"(p10[2]), "v"(p10[3]));
      asm("v_cvt_pk_bf16_f32 %0, %1, %2" : "=v"(c6) : "v"(p11[0]), "v"(p11[1]));
      asm("v_cvt_pk_bf16_f32 %0, %1, %2" : "=v"(c7) : "v"(p11[2]), "v"(p11[3]));
      union { unsigned u[4]; short8 s; } pa, pb;
      pa.u[0] = c0; pa.u[1] = c1; pa.u[2] = c2; pa.u[3] = c3;
      pb.u[0] = c4; pb.u[1] = c5; pb.u[2] = c6; pb.u[3] = c7;
      o00 = __builtin_amdgcn_mfma_f32_16x16x32_bf16(va0, pa.s, o00, 0, 0, 0);
      o01 = __builtin_amdgcn_mfma_f32_16x16x32_bf16(va1, pa.s, o01, 0, 0, 0);
      o10 = __builtin_amdgcn_mfma_f32_16x16x32_bf16(va0, pb.s, o10, 0, 0, 0);
      o11 = __builtin_amdgcn_mfma_f32_16x16x32_bf16(va1, pb.s, o11, 0, 0, 0);
      lacc0 = __builtin_amdgcn_mfma_f32_16x16x32_bf16(vones, pa.s, lacc0, 0, 0, 0);
      lacc1 = __builtin_amdgcn_mfma_f32_16x16x32_bf16(vones, pb.s, lacc1, 0, 0, 0);
    }
  }
  asm volatile("s_waitcnt vmcnt(0)" ::: "memory");
  const float ls0 = lacc0[0], ls1 = lacc1[0];   // all regs/lane-groups equal
  unsigned short* po = part_ob + (((size_t)(chunk * 16 + bh) * NSEQ) + qbase + r) * HD;
  short4v w0, w1, w2, w3;
  #pragma unroll
  for (int j = 0; j < 4; j++){
    w0[j] = (short)f2bf(o00[j]); w1[j] = (short)f2bf(o01[j]);
    w2[j] = (short)f2bf(o10[j]); w3[j] = (short)f2bf(o11[j]);
  }
  *(short4v*)(po + cg * 4)              = w0;
  *(short4v*)(po + 16 + cg * 4)         = w1;
  *(short4v*)(po + 16 * HD + cg * 4)    = w2;
  *(short4v*)(po + 16 * HD + 16 + cg * 4) = w3;
  if (lane < 16){
    part_l[(size_t)(chunk * 16 + bh) * NSEQ + qbase + r] = ls0;
    part_l[(size_t)(chunk * 16 + bh) * NSEQ + qbase + 16 + r] = ls1;
  }
}

// ---------------- K3: fused reduce+proj+LN2+MLP1+GELU+MLP2 (16 tok/block) ---
// 1024 blocks, 512 threads, 28KB LDS -> 3-4 blocks/CU.
__global__ __launch_bounds__(512, 4) void k_fused(
    const unsigned short* __restrict__ part_ob, const float* __restrict__ part_l,
    const float* __restrict__ x, const unsigned short* __restrict__ wpack,
    const float* __restrict__ pb, const float* __restrict__ g2,
    const float* __restrict__ b2, const float* __restrict__ b1,
    const float* __restrict__ b2m, float* __restrict__ out)
{
  __shared__ float sb[16 * 128];             //  8KB residual (x + attn@proj)
  __shared__ unsigned short hfr[2048];       //  4KB LN2 output, A-frag layout
  __shared__ unsigned short afr[8192];       // 16KB GELU acts, A-frag layout
  const int tid = threadIdx.x, tok0 = blockIdx.x * 16;
  const int wv = tid >> 6, lane = tid & 63, r = lane & 15, cg = lane >> 4;
  const int bidx = tok0 >> 12, qn0 = (tok0 & (NSEQ - 1)) + r;
  // ---- phase A: softmax-reduce -> proj A-frag (per-wave); proj ct = wv
  short8 af[4];
  #pragma unroll
  for (int kt = 0; kt < 4; kt++){
    const int bh = bidx * 4 + kt;
    float s8[8] = {0.f,0.f,0.f,0.f,0.f,0.f,0.f,0.f};
    float lsum = 0.f;
    #pragma unroll
    for (int c = 0; c < 2; c++){
      const short8 v = *(const short8*)(part_ob +
          (((size_t)(c * 16 + bh) * NSEQ) + qn0) * HD + cg * 8);
      #pragma unroll
      for (int i = 0; i < 8; i++) s8[i] += bf2f((unsigned short)v[i]);
      lsum += part_l[(size_t)(c * 16 + bh) * NSEQ + qn0];
    }
    const float inv = 1.f / lsum;
    #pragma unroll
    for (int i = 0; i < 8; i++) af[kt][i] = (short)f2bf(s8[i] * inv);
  }
  {
    const unsigned short* wp = wpack + 49152;
    f32x4 acc = {0.f, 0.f, 0.f, 0.f};
    const unsigned short* bp = wp + ((size_t)(wv * 4) * 64 + lane) * 8;
    #pragma unroll
    for (int kt = 0; kt < 4; kt++)
      acc = __builtin_amdgcn_mfma_f32_16x16x32_bf16(af[kt], *(const short8*)(bp + kt * 512), acc, 0, 0, 0);
    const int col = wv * 16 + r;
    const float bi = pb[col];
    #pragma unroll
    for (int reg = 0; reg < 4; reg++){
      const int tl = cg * 4 + reg;
      sb[tl * 128 + col] = acc[reg] + bi + x[(size_t)(tok0 + tl) * 128 + col];
    }
  }
  __syncthreads();
  // ---- phase B: LN2 -> hfr (A-fragment layout in LDS); 1 row per 32 lanes
  {
    const int t = tid >> 5, l = tid & 31;
    const float4 xv = *(const float4*)(sb + t * 128 + l * 4);
    float s  = xv.x + xv.y + xv.z + xv.w;
    float s2 = xv.x*xv.x + xv.y*xv.y + xv.z*xv.z + xv.w*xv.w;
    #pragma unroll
    for (int m = 1; m <= 16; m <<= 1){ s += __shfl_xor(s, m); s2 += __shfl_xor(s2, m); }
    const float mu = s * (1.f/128.f);
    const float rs = rsqrtf(s2 * (1.f/128.f) - mu*mu + 1e-5f);
    const int e = l * 4;
    const float4 gv = *(const float4*)(g2 + e), bv = *(const float4*)(b2 + e);
    short4v pk;
    pk[0] = (short)f2bf((xv.x - mu)*rs*gv.x + bv.x);
    pk[1] = (short)f2bf((xv.y - mu)*rs*gv.y + bv.y);
    pk[2] = (short)f2bf((xv.z - mu)*rs*gv.z + bv.z);
    pk[3] = (short)f2bf((xv.w - mu)*rs*gv.w + bv.w);
    *(short4v*)(&hfr[(e >> 3) * 128 + t * 8 + (e & 7)]) = pk;
  }
  __syncthreads();
  // ---- phase C: MLP1 + GELU -> afr (A-frag); cts = wv*4 .. wv*4+4
  {
    short8 hf[4];
    #pragma unroll
    for (int kt = 0; kt < 4; kt++)
      hf[kt] = *(const short8*)(&hfr[(kt * 4 + cg) * 128 + r * 8]);
    const unsigned short* w1 = wpack + 65536;
    for (int ct = wv * 4; ct < wv * 4 + 4; ct++){
      f32x4 acc = {0.f, 0.f, 0.f, 0.f};
      const unsigned short* bp = w1 + ((size_t)(ct * 4) * 64 + lane) * 8;
      #pragma unroll
      for (int kt = 0; kt < 4; kt++)
        acc = __builtin_amdgcn_mfma_f32_16x16x32_bf16(hf[kt], *(const short8*)(bp + kt * 512), acc, 0, 0, 0);
      const int col = ct * 16 + r;
      const float bi = b1[col];
      #pragma unroll
      for (int reg = 0; reg < 4; reg++){
        const float v = acc[reg] + bi;
        const float ge = 0.5f * v * (1.f + erff(v * 0.70710678118f));
        afr[(col >> 3) * 128 + (cg * 4 + reg) * 8 + (col & 7)] = f2bf(ge);
      }
    }
  }
  __syncthreads();
  // ---- phase D: MLP2 + residual (sb) -> out; output ct = wv
  {
    const unsigned short* w2 = wpack + 131072;
    f32x4 acc = {0.f,0.f,0.f,0.f};
    for (int kt = 0; kt < 16; kt++){
      const short8 a3 = *(const short8*)(&afr[(kt * 4 + cg) * 128 + r * 8]);
      const unsigned short* bp = w2 + ((size_t)(wv * 16 + kt) * 64 + lane) * 8;
      acc = __builtin_amdgcn_mfma_f32_16x16x32_bf16(a3, *(const short8*)(bp), acc, 0, 0, 0);
    }
    const int col = wv * 16 + r;
    const float bi = b2m[col];
    #pragma unroll
    for (int reg = 0; reg < 4; reg++){
      const int tl = cg * 4 + reg;
      out[(size_t)(tok0 + tl) * 128 + col] = acc[reg] + bi + sb[tl * 128 + col];
    }
  }
}

extern "C" void kernel_launch(void* const* d_in, const int* in_sizes, int n_in,
                              void* d_out, int out_size, void* d_ws, size_t ws_size,
                              hipStream_t stream)
{
  const float* x      = (const float*)d_in[0];
  const float* ln1_g  = (const float*)d_in[1];
  const float* ln1_b  = (const float*)d_in[2];
  const float* qkv_w  = (const float*)d_in[3];
  const float* qkv_b  = (const float*)d_in[4];
  const float* proj_w = (const float*)d_in[5];
  const float* proj_b = (const float*)d_in[6];
  const float* ln2_g  = (const float*)d_in[7];
  const float* ln2_b  = (const float*)d_in[8];
  const float* mlp_w1 = (const float*)d_in[9];
  const float* mlp_b1 = (const float*)d_in[10];
  const float* mlp_w2 = (const float*)d_in[11];
  const float* mlp_b2 = (const float*)d_in[12];

  char* ws = (char*)d_ws;
  unsigned short* wpack   = (unsigned short*)(ws);
  float*          bqs     = (float*)(ws + 393216);
  unsigned short* qkv     = (unsigned short*)(ws + 524288);
  unsigned short* part_ob = (unsigned short*)(ws + 13107200);
  float*          part_l  = (float*)(ws + 29884416);
  float* out = (float*)d_out;

  hipLaunchKernelGGL(k_pack, dim3(96), dim3(256), 0, stream,
                     qkv_w, qkv_b, proj_w, mlp_w1, mlp_w2, wpack, bqs);
  hipLaunchKernelGGL(k_qkv, dim3(512), dim3(512), 0, stream,
                     x, ln1_g, ln1_b, wpack, bqs, qkv);
  hipLaunchKernelGGL(k_attn, dim3(32, 2, 16), dim3(256), 0, stream,
                     qkv, part_ob, part_l);
  hipLaunchKernelGGL(k_fused, dim3(1024), dim3(512), 0, stream,
                     part_ob, part_l, x, wpack, proj_b, ln2_g, ln2_b,
                     mlp_b1, mlp_b2, out);
}